// Round 4
// baseline (68574.463 us; speedup 1.0000x reference)
//
#include <hip/hip_runtime.h>
#include <hip/hip_bf16.h>

#define NEDGE 640000
#define NMAX  40000
#define SB    40      // scan blocks
#define PBLK  256     // pool blocks
#define EBLK  320     // edge-compact blocks
#define FB    1280    // fill blocks (128 thr each)
#define LIN1B 64      // lin1 partial blocks
#define GRB   32      // gemm rows per block

// ---------------------------------------------------------------- helpers
__device__ inline void atomicMaxF(float* addr, float val) {
    unsigned* ua = (unsigned*)addr;
    unsigned old = *ua;
    while (__uint_as_float(old) < val) {
        unsigned assumed = old;
        old = atomicCAS(ua, assumed, __float_as_uint(val));
        if (old == assumed) break;
    }
}

__device__ inline unsigned orderKey(float s) {
    unsigned b = __float_as_uint(s);
    return (b & 0x80000000u) ? ~b : (b | 0x80000000u);
}

__device__ const float c_invk[10] = {
    1.0f/32000.0f, 1.0f/25600.0f, 1.0f/20480.0f, 1.0f/16384.0f, 1.0f/13108.0f,
    1.0f/10487.0f, 1.0f/8390.0f,  1.0f/6712.0f,  1.0f/5370.0f,  1.0f/4296.0f };

// selbuf slots: 0=bstar 1=rem 2=candcnt 5=slotcnt

// ---------------------------------------------------------------- init (+ layer-0 degree count)
__global__ void k_init(const int* __restrict__ eidx, int* __restrict__ esrc,
                       int* __restrict__ edst, const float* __restrict__ poolp,
                       float* __restrict__ rbuf, float* __restrict__ pnorm,
                       int* __restrict__ ecnt, int* __restrict__ degA) {
    int b = blockIdx.x, t = threadIdx.x;
    if (b < 10) {
        rbuf[b*256 + t] = (t < 128) ? -3.402823e38f : 0.0f;
        __shared__ float red[256];
        float v = 0.0f;
        if (t < 128) { float pv = poolp[b*128 + t]; v = pv*pv; }
        red[t] = v; __syncthreads();
        for (int s = 128; s > 0; s >>= 1) { if (t < s) red[t] += red[t+s]; __syncthreads(); }
        if (t == 0) pnorm[b] = sqrtf(red[0]);
    }
    if (b == 10 && t < 16) ecnt[t] = (t == 0) ? NEDGE : 0;
    int e = b*256 + t;
    if (e < NEDGE) {
        int d = eidx[NEDGE + e];
        esrc[e] = eidx[e]; edst[e] = d;
        atomicAdd(&degA[d], 1);
    }
}

// ---------------------------------------------------------------- scan pass 1 (+ per-layer zeroing)
__global__ void k_s1(const int* __restrict__ deg, int* __restrict__ bpart,
                     int* __restrict__ ghist, int* __restrict__ selbuf, int n, int chunk) {
    int b = blockIdx.x, t = threadIdx.x;
    if (b == 0) {
        for (int jj = t; jj < 2048; jj += 256) ghist[jj] = 0;
        if (t == 0) { selbuf[2] = 0; selbuf[5] = 0; }
    }
    int start = b*chunk, end = min(start + chunk, n);
    int s = 0;
    for (int i = start + t; i < end; i += 256) s += deg[i];
    __shared__ int red[256];
    red[t] = s; __syncthreads();
    for (int st = 128; st > 0; st >>= 1) { if (t < st) red[t] += red[t+st]; __syncthreads(); }
    if (t == 0) bpart[b] = red[0];
}

// ---------------------------------------------------------------- scan pass 2
__global__ void k_s3(const int* __restrict__ deg, const int* __restrict__ bpart,
                     int* __restrict__ offs, int* __restrict__ cursor,
                     float* __restrict__ dinv, int n, int chunk) {
    int b = blockIdx.x, t = threadIdx.x, lane = t & 63, wid = t >> 6;
    __shared__ int wsum[4];
    __shared__ int s_carry;
    if (t < 64) {
        int v = (lane < b) ? bpart[lane] : 0;
        for (int off = 32; off > 0; off >>= 1) v += __shfl_down(v, off);
        if (lane == 0) s_carry = v;
    }
    __syncthreads();
    int start = b*chunk, end = min(start + chunk, n);
    for (int base = start; base < end; base += 256) {
        int i = base + t;
        int d = (i < end) ? deg[i] : 0;
        int incl = d;
        for (int off = 1; off < 64; off <<= 1) {
            int o = __shfl_up(incl, off);
            if (lane >= off) incl += o;
        }
        if (lane == 63) wsum[wid] = incl;
        __syncthreads();
        if (t == 0) { int c = s_carry; for (int w = 0; w < 4; w++) { int tmp = wsum[w]; wsum[w] = c; c += tmp; } s_carry = c; }
        __syncthreads();
        int p = wsum[wid] + incl - d;
        if (i < end) {
            offs[i] = p; cursor[i] = p;
            dinv[i] = (d > 0) ? 1.0f/sqrtf((float)d) : 0.0f;
        }
        __syncthreads();
    }
}

// ---------------------------------------------------------------- fused CSR fill + GEMM
__global__ __launch_bounds__(128) void k_fillgemm(const int* __restrict__ esrc, const int* __restrict__ edst,
        int* __restrict__ cursor, int* __restrict__ csr, const int* __restrict__ ecnt,
        const float* __restrict__ h, const float* __restrict__ W, const float* __restrict__ V,
        const float* __restrict__ bias, float* __restrict__ HW, float* __restrict__ AGG, int n) {
    int b = blockIdx.x, t = threadIdx.x;
    __shared__ __align__(16) float ht[128*36];
    if (b < FB) {
        int ec = *ecnt;
        for (int e = b*128 + t; e < ec; e += FB*128) {
            int pos = atomicAdd(&cursor[edst[e]], 1);
            csr[pos] = esrc[e];
        }
        return;
    }
    int v0 = (b - FB) * GRB;
    for (int it = 0; it < GRB; it++) {
        ht[t*36 + it] = h[(v0 + it)*128 + t];
    }
    __syncthreads();
    float accW[GRB], accV[GRB];
    #pragma unroll
    for (int r = 0; r < GRB; r++) { accW[r] = 0.0f; accV[r] = 0.0f; }
    for (int k = 0; k < 128; k++) {
        float mw = W[k*128 + t];
        float mv = V[k*128 + t];
        const float* hp = &ht[k*36];
        #pragma unroll
        for (int r4 = 0; r4 < GRB; r4 += 4) {
            float4 hq = *(const float4*)(hp + r4);
            accW[r4+0] += hq.x*mw;  accV[r4+0] += hq.x*mv;
            accW[r4+1] += hq.y*mw;  accV[r4+1] += hq.y*mv;
            accW[r4+2] += hq.z*mw;  accV[r4+2] += hq.z*mv;
            accW[r4+3] += hq.w*mw;  accV[r4+3] += hq.w*mv;
        }
    }
    float bb = bias[t];
    for (int r = 0; r < GRB; r++) {
        int v = v0 + r;
        if (v >= n) break;
        HW[v*128 + t]  = accW[r];
        AGG[v*128 + t] = accV[r] + bb;
    }
}

// ---------------------------------------------------------------- layer-0 fused node update (+hist)
__global__ __launch_bounds__(128) void k_gather0(
    const float* __restrict__ x, const float* __restrict__ W1, const float* __restrict__ V1,
    const float* __restrict__ convb,
    const float* __restrict__ bng, const float* __restrict__ bnb,
    const float* __restrict__ bnm, const float* __restrict__ bnv,
    const float* __restrict__ poolp, const float* __restrict__ pnorm,
    const float* __restrict__ prelua,
    const int* __restrict__ offs, const int* __restrict__ deg, const float* __restrict__ dinv,
    const int* __restrict__ csr,
    float* __restrict__ AGG, float* __restrict__ score, unsigned* __restrict__ keys,
    int* __restrict__ ghist) {
    int v = blockIdx.x, j = threadIdx.x;
    __shared__ float red[128];
    int off = offs[v], dg = deg[v];
    float accs = 0.0f;
    for (int c = j; c < dg; c += 128) { int s = csr[off + c]; accs += x[s]*dinv[s]; }
    red[j] = accs; __syncthreads();
    for (int st = 64; st > 0; st >>= 1) { if (j < st) red[j] += red[j+st]; __syncthreads(); }
    float aggs = red[0] * dinv[v];
    __syncthreads();
    float h2 = aggs*W1[j] + x[v]*V1[j] + convb[j];
    h2 = fmaxf(h2, 0.0f);
    float scale = bng[j] / sqrtf(bnv[j] + 1e-5f);
    h2 = (h2 - bnm[j])*scale + bnb[j];
    float a = prelua[0];
    h2 = (h2 > 0.0f) ? h2 : a*h2;
    AGG[v*128 + j] = h2;
    red[j] = h2 * poolp[j]; __syncthreads();
    for (int st = 64; st > 0; st >>= 1) { if (j < st) red[j] += red[j+st]; __syncthreads(); }
    if (j == 0) {
        float sc = tanhf(red[0] / pnorm[0]);
        unsigned key = orderKey(sc);
        score[v] = sc;
        keys[v]  = key;
        atomicAdd(&ghist[key >> 21], 1);
    }
}

// ---------------------------------------------------------------- generic fused gather + update + score (+hist)
__global__ __launch_bounds__(128) void k_gather(
    const float* __restrict__ HW, float* __restrict__ AGG,
    const int* __restrict__ offs, const int* __restrict__ deg, const float* __restrict__ dinv,
    const int* __restrict__ csr,
    const float* __restrict__ bng, const float* __restrict__ bnb,
    const float* __restrict__ bnm, const float* __restrict__ bnv,
    const float* __restrict__ poolp, const float* __restrict__ pnorm,
    const float* __restrict__ prelua,
    float* __restrict__ score, unsigned* __restrict__ keys, int* __restrict__ ghist, int layer) {
    int v = blockIdx.x, j = threadIdx.x;
    __shared__ int   s_src[128];
    __shared__ float s_dv[128];
    __shared__ float red[128];
    int off = offs[v], dg = deg[v];
    float acc = 0.0f;
    for (int base = 0; base < dg; base += 128) {
        int cnt = min(128, dg - base);
        if (j < cnt) { int s = csr[off + base + j]; s_src[j] = s; s_dv[j] = dinv[s]; }
        __syncthreads();
        for (int c = 0; c < cnt; c++) acc += HW[s_src[c]*128 + j] * s_dv[c];
        __syncthreads();
    }
    int gj = layer*128 + j;
    float h2 = AGG[v*128 + j] + acc*dinv[v];
    h2 = fmaxf(h2, 0.0f);
    float scale = bng[gj] / sqrtf(bnv[gj] + 1e-5f);
    h2 = (h2 - bnm[gj])*scale + bnb[gj];
    float a = prelua[0];
    h2 = (h2 > 0.0f) ? h2 : a*h2;
    AGG[v*128 + j] = h2;
    red[j] = h2 * poolp[gj]; __syncthreads();
    for (int st = 64; st > 0; st >>= 1) { if (j < st) red[j] += red[j+st]; __syncthreads(); }
    if (j == 0) {
        float sc = tanhf(red[0] / pnorm[layer]);
        unsigned key = orderKey(sc);
        score[v] = sc;
        keys[v]  = key;
        atomicAdd(&ghist[key >> 21], 1);
    }
}

// ---------------------------------------------------------------- top-k stage 1: bin select + candidate collect (+degN zero)
__global__ __launch_bounds__(1024) void k_collect(const unsigned* __restrict__ keys,
                                                  const int* __restrict__ ghist,
                                                  int* __restrict__ selbuf,
                                                  unsigned* __restrict__ ckey, int* __restrict__ cidx,
                                                  int* __restrict__ degN, int n, int kk) {
    __shared__ int sh[2048];
    __shared__ int s_bstar, s_base, s_cur;
    __shared__ int red[1024];
    int t = threadIdx.x, lane = t & 63;
    for (int i = blockIdx.x*1024 + t; i < NMAX; i += gridDim.x*1024) degN[i] = 0;
    sh[t] = ghist[t]; sh[t+1024] = ghist[t+1024];
    __syncthreads();
    for (int off = 1; off < 2048; off <<= 1) {
        int v0 = sh[t]      + ((t+off < 2048)      ? sh[t+off]      : 0);
        int v1 = sh[t+1024] + ((t+1024+off < 2048) ? sh[t+1024+off] : 0);
        __syncthreads();
        sh[t] = v0; sh[t+1024] = v1;
        __syncthreads();
    }
    for (int d = t; d < 2048; d += 1024) {
        int S = sh[d], Sn = (d == 2047) ? 0 : sh[d+1];
        if (S >= kk && Sn < kk) {
            s_bstar = d;
            if (blockIdx.x == 0) { selbuf[0] = d; selbuf[1] = kk - Sn; }
        }
    }
    __syncthreads();
    int bstar = s_bstar;
    int cnt = 0;
    for (int i = blockIdx.x*1024 + t; i < n; i += gridDim.x*1024)
        cnt += ((int)(keys[i] >> 21) == bstar);
    red[t] = cnt; __syncthreads();
    for (int st = 512; st > 0; st >>= 1) { if (t < st) red[t] += red[t+st]; __syncthreads(); }
    if (t == 0) { s_base = atomicAdd(&selbuf[2], red[0]); s_cur = 0; }
    __syncthreads();
    for (int base = blockIdx.x*1024; base < n; base += gridDim.x*1024) {
        int i = base + t;
        bool keep = false; unsigned key = 0;
        if (i < n) { key = keys[i]; keep = ((int)(key >> 21) == bstar); }
        unsigned long long m = __ballot(keep);
        int wcnt = __popcll(m);
        int wbase = 0;
        if (lane == 0 && wcnt) wbase = atomicAdd(&s_cur, wcnt);
        wbase = __shfl(wbase, 0);
        if (keep) {
            int pos = s_base + wbase + __popcll(m & ((1ULL << lane) - 1));
            ckey[pos] = key; cidx[pos] = i;
        }
    }
}

// ---------------------------------------------------------------- top-k stage 2: exact rank of candidates
__global__ __launch_bounds__(1024) void k_rank(const unsigned* __restrict__ ckey,
                                               const int* __restrict__ cidx,
                                               const int* __restrict__ selbuf,
                                               int* __restrict__ tflag) {
    __shared__ unsigned skey[2048];
    __shared__ int sidx[2048];
    int t = threadIdx.x;
    int m = selbuf[2], rem = selbuf[1];
    for (int cb = 0; cb < m; cb += 8192) {
        unsigned myk[8]; int myi[8]; int rk[8];
        #pragma unroll
        for (int q = 0; q < 8; q++) {
            int c = cb + q*1024 + t;
            rk[q] = 0; myk[q] = 0; myi[q] = 0;
            if (c < m) { myk[q] = ckey[c]; myi[q] = cidx[c]; }
        }
        for (int tb = 0; tb < m; tb += 2048) {
            int tcnt = min(2048, m - tb);
            __syncthreads();
            if (t < tcnt)      { skey[t]      = ckey[tb+t];      sidx[t]      = cidx[tb+t]; }
            if (t+1024 < tcnt) { skey[t+1024] = ckey[tb+t+1024]; sidx[t+1024] = cidx[tb+t+1024]; }
            __syncthreads();
            #pragma unroll
            for (int q = 0; q < 8; q++) {
                int c = cb + q*1024 + t;
                if (c >= m) break;
                unsigned kc = myk[q]; int ic = myi[q]; int r = rk[q];
                for (int jj = 0; jj < tcnt; jj++) {
                    unsigned kj = skey[jj]; int ij = sidx[jj];
                    r += (kj > kc) || (kj == kc && ij < ic);
                }
                rk[q] = r;
            }
        }
        #pragma unroll
        for (int q = 0; q < 8; q++) {
            int c = cb + q*1024 + t;
            if (c < m) tflag[myi[q]] = (rk[q] < rem) ? 1 : 0;
        }
        __syncthreads();
    }
}

// ---------------------------------------------------------------- top-k stage 3: compaction
__global__ void k_compact(const unsigned* __restrict__ keys, int* __restrict__ selbuf,
                          const int* __restrict__ tflag,
                          int* __restrict__ remap, int* __restrict__ keep_ids, int n) {
    int bstar = selbuf[0];
    int t = threadIdx.x, lane = t & 63;
    __shared__ int s_base, s_cur;
    __shared__ int red[256];
    int cnt = 0;
    for (int base = blockIdx.x*256; base < n; base += gridDim.x*256) {
        int i = base + t;
        if (i < n) {
            int bin = (int)(keys[i] >> 21);
            cnt += (bin > bstar) || (bin == bstar && tflag[i]);
        }
    }
    red[t] = cnt; __syncthreads();
    for (int st = 128; st > 0; st >>= 1) { if (t < st) red[t] += red[t+st]; __syncthreads(); }
    if (t == 0) { s_base = atomicAdd(&selbuf[5], red[0]); s_cur = 0; }
    __syncthreads();
    for (int base = blockIdx.x*256; base < n; base += gridDim.x*256) {
        int i = base + t;
        bool keep = false;
        if (i < n) {
            int bin = (int)(keys[i] >> 21);
            keep = (bin > bstar) || (bin == bstar && tflag[i]);
        }
        unsigned long long m = __ballot(keep);
        int wcnt = __popcll(m);
        int wbase = 0;
        if (lane == 0 && wcnt) wbase = atomicAdd(&s_cur, wcnt);
        wbase = __shfl(wbase, 0);
        if (keep) {
            int slot = s_base + wbase + __popcll(m & ((1ULL << lane) - 1));
            remap[i] = slot; keep_ids[slot] = i;
        } else if (i < n) remap[i] = -1;
    }
}

// ---------------------------------------------------------------- pool + edge remap/compact (+next-layer degree)
__global__ void k_pool(const float* __restrict__ AGG, const float* __restrict__ score,
                       const int* __restrict__ keep_ids, const int* __restrict__ remap,
                       float* __restrict__ H, float* __restrict__ rbuf,
                       const int* __restrict__ esrcP, const int* __restrict__ edstP,
                       int* __restrict__ esrcN, int* __restrict__ edstN,
                       const int* __restrict__ ecntP, int* __restrict__ ecntN,
                       int* __restrict__ degN, int k, int layer) {
    int b = blockIdx.x, t = threadIdx.x;
    if (b < PBLK) {
        int sub = t >> 7, j = t & 127;
        float lmax = -3.402823e38f, lsum = 0.0f;
        int s = b*2 + sub;
        int v = (s < k) ? keep_ids[s] : 0;
        while (s < k) {
            float sc = score[v];
            float val = AGG[v*128 + j] * sc;
            int s2 = s + PBLK*2;
            int v2 = (s2 < k) ? keep_ids[s2] : 0;
            H[s*128 + j] = val;
            lmax = fmaxf(lmax, val); lsum += val;
            s = s2; v = v2;
        }
        __shared__ float shm[256], shs[256];
        shm[t] = lmax; shs[t] = lsum;
        __syncthreads();
        if (sub == 0) {
            lmax = fmaxf(shm[j], shm[j+128]);
            lsum = shs[j] + shs[j+128];
            atomicMaxF(&rbuf[layer*256 + j], lmax);
            atomicAdd(&rbuf[layer*256 + 128 + j], lsum);
        }
    } else {
        int eb = b - PBLK, lane = t & 63;
        int ec = *ecntP;
        __shared__ int s_base, s_cur;
        __shared__ int red[256];
        int cnt = 0;
        for (int base = eb*256; base < ec; base += EBLK*256) {
            int e = base + t;
            if (e < ec) {
                int ns = remap[esrcP[e]], nd = remap[edstP[e]];
                cnt += (ns >= 0 && nd >= 0);
            }
        }
        red[t] = cnt; __syncthreads();
        for (int st = 128; st > 0; st >>= 1) { if (t < st) red[t] += red[t+st]; __syncthreads(); }
        if (t == 0) { s_base = atomicAdd(ecntN, red[0]); s_cur = 0; }
        __syncthreads();
        for (int base = eb*256; base < ec; base += EBLK*256) {
            int e = base + t;
            bool keep = false; int ns = 0, nd = 0;
            if (e < ec) {
                ns = remap[esrcP[e]]; nd = remap[edstP[e]];
                keep = (ns >= 0 && nd >= 0);
            }
            unsigned long long m = __ballot(keep);
            int wcnt = __popcll(m);
            int wbase = 0;
            if (lane == 0 && wcnt) wbase = atomicAdd(&s_cur, wcnt);
            wbase = __shfl(wbase, 0);
            if (keep) {
                int pos = s_base + wbase + __popcll(m & ((1ULL << lane) - 1));
                esrcN[pos] = ns; edstN[pos] = nd;
                atomicAdd(&degN[nd], 1);
            }
        }
    }
}

// ---------------------------------------------------------------- MLP head
__global__ __launch_bounds__(320) void k_lin1(const float* __restrict__ rbuf,
                                              const float* __restrict__ w1,
                                              float* __restrict__ z1part) {
    int b = blockIdx.x, t = threadIdx.x;
    int j = t*4;
    float4 acc = make_float4(0.f, 0.f, 0.f, 0.f);
    int i0 = b*40;
    for (int r = 0; r < 40; r++) {
        int i = i0 + r;
        float rv = rbuf[i];
        if (i & 128) rv *= c_invk[i >> 8];
        float4 w = *(const float4*)(w1 + (size_t)i*1280 + j);
        acc.x += rv*w.x; acc.y += rv*w.y; acc.z += rv*w.z; acc.w += rv*w.w;
    }
    *(float4*)(z1part + b*1280 + j) = acc;
}

__global__ __launch_bounds__(320) void k_lin2(const float* __restrict__ z1part,
                                              const float* __restrict__ b1,
                                              const float* __restrict__ w2, const float* __restrict__ b2,
                                              const float* __restrict__ prelua, float* __restrict__ out) {
    int t = threadIdx.x, lane = t & 63, wid = t >> 6;
    float a = prelua[0];
    int j = t*4;
    float4 acc = make_float4(0.f, 0.f, 0.f, 0.f);
    for (int p = 0; p < LIN1B; p++) {
        float4 v = *(const float4*)(z1part + p*1280 + j);
        acc.x += v.x; acc.y += v.y; acc.z += v.z; acc.w += v.w;
    }
    float4 bb = *(const float4*)(b1 + j);
    float z0 = acc.x + bb.x; z0 = z0 > 0.f ? z0 : a*z0;
    float z1 = acc.y + bb.y; z1 = z1 > 0.f ? z1 : a*z1;
    float z2 = acc.z + bb.z; z2 = z2 > 0.f ? z2 : a*z2;
    float z3 = acc.w + bb.w; z3 = z3 > 0.f ? z3 : a*z3;
    float s[8];
    #pragma unroll
    for (int o = 0; o < 8; o++)
        s[o] = z0*w2[(j+0)*8+o] + z1*w2[(j+1)*8+o] + z2*w2[(j+2)*8+o] + z3*w2[(j+3)*8+o];
    #pragma unroll
    for (int off = 32; off > 0; off >>= 1)
        #pragma unroll
        for (int o = 0; o < 8; o++) s[o] += __shfl_down(s[o], off);
    __shared__ float sred[5][8];
    if (lane == 0)
        for (int o = 0; o < 8; o++) sred[wid][o] = s[o];
    __syncthreads();
    if (t == 0) {
        float zo[8];
        for (int o = 0; o < 8; o++) {
            float z = sred[0][o]+sred[1][o]+sred[2][o]+sred[3][o]+sred[4][o] + b2[o];
            zo[o] = z > 0.f ? z : a*z;
        }
        float mn = zo[0];
        for (int o = 1; o < 8; o++) mn = fminf(mn, zo[o]);
        float v[8], mx = -3.402823e38f;
        for (int o = 0; o < 8; o++) { v[o] = zo[o] - mn; mx = fmaxf(mx, v[o]); }
        float sm = 0.f;
        for (int o = 0; o < 8; o++) { v[o] = v[o] / mx; sm += v[o]; }
        for (int o = 0; o < 8; o++) out[o] = v[o] / sm;
    }
}

// ---------------------------------------------------------------- launch
extern "C" void kernel_launch(void* const* d_in, const int* in_sizes, int n_in,
                              void* d_out, int out_size, void* d_ws, size_t ws_size,
                              hipStream_t stream) {
    const float* x      = (const float*)d_in[0];
    const int*   eidx   = (const int*)  d_in[1];
    const float* W1     = (const float*)d_in[2];
    const float* V1     = (const float*)d_in[3];
    const float* Ws     = (const float*)d_in[4];
    const float* Vs     = (const float*)d_in[5];
    const float* convb  = (const float*)d_in[6];
    const float* bng    = (const float*)d_in[7];
    const float* bnb    = (const float*)d_in[8];
    const float* bnm    = (const float*)d_in[9];
    const float* bnv    = (const float*)d_in[10];
    const float* poolp  = (const float*)d_in[11];
    const float* prelua = (const float*)d_in[12];
    const float* w1     = (const float*)d_in[13];
    const float* b1     = (const float*)d_in[14];
    const float* w2     = (const float*)d_in[15];
    const float* b2     = (const float*)d_in[16];
    float* out = (float*)d_out;

    float* wsf  = (float*)d_ws;
    float* H      = wsf;
    float* HW     = H     + (size_t)NMAX*128;
    float* AGG    = HW    + (size_t)NMAX*128;
    float* dinv   = AGG   + (size_t)NMAX*128;
    float* score  = dinv  + NMAX;
    float* rbuf   = score + NMAX;
    float* pnorm  = rbuf  + 2560;
    float* z1part = pnorm + 16;                  // LIN1B*1280
    unsigned* keys = (unsigned*)(z1part + LIN1B*1280);
    int* esrcA  = (int*)(keys + NMAX);
    int* edstA  = esrcA + NEDGE;
    int* esrcB  = edstA + NEDGE;
    int* edstB  = esrcB + NEDGE;
    int* csr    = edstB + NEDGE;
    int* degA   = csr   + NEDGE;
    int* degB   = degA  + NMAX;
    int* ghist  = degB  + NMAX;                  // 2048
    int* offs   = ghist + 2048;
    int* cursor = offs  + NMAX;                  // doubles as tflag after fill
    int* remap  = cursor + NMAX;
    int* keep_ids = remap + NMAX;
    unsigned* ckey = (unsigned*)(keep_ids + NMAX);
    int* cidx   = (int*)(ckey + NMAX);
    int* bpart  = cidx  + NMAX;                  // 64
    int* ecnt   = bpart + 64;                    // 16
    int* selbuf = ecnt  + 16;                    // 16

    static const int NS[10] = {40000,32000,25600,20480,16384,13108,10487,8390,6712,5370};
    static const int KS[10] = {32000,25600,20480,16384,13108,10487,8390,6712,5370,4296};

    hipMemsetAsync(degA, 0, (size_t)NMAX*sizeof(int), stream);
    k_init<<<2500, 256, 0, stream>>>(eidx, esrcA, edstA, poolp, rbuf, pnorm, ecnt, degA);

    for (int i = 0; i < 10; i++) {
        int n = NS[i], k = KS[i];
        int chunk = (n + SB - 1) / SB;
        int* esrcP = (i & 1) ? esrcB : esrcA;
        int* edstP = (i & 1) ? edstB : edstA;
        int* esrcN = (i & 1) ? esrcA : esrcB;
        int* edstN = (i & 1) ? edstA : edstB;
        int* degP  = (i & 1) ? degB : degA;
        int* degN  = (i & 1) ? degA : degB;

        k_s1<<<SB, 256, 0, stream>>>(degP, bpart, ghist, selbuf, n, chunk);
        k_s3<<<SB, 256, 0, stream>>>(degP, bpart, offs, cursor, dinv, n, chunk);

        int gb = (i == 0) ? 0 : (n + GRB - 1) / GRB;
        k_fillgemm<<<FB + gb, 128, 0, stream>>>(esrcP, edstP, cursor, csr, &ecnt[i],
                                                H, (i == 0) ? W1 : Ws + (size_t)(i-1)*16384,
                                                (i == 0) ? V1 : Vs + (size_t)(i-1)*16384,
                                                convb + i*128, HW, AGG, n);

        if (i == 0) {
            k_gather0<<<n, 128, 0, stream>>>(x, W1, V1, convb,
                                             bng, bnb, bnm, bnv, poolp, pnorm, prelua,
                                             offs, degP, dinv, csr, AGG, score, keys, ghist);
        } else {
            k_gather<<<n, 128, 0, stream>>>(HW, AGG, offs, degP, dinv, csr,
                                            bng, bnb, bnm, bnv, poolp, pnorm, prelua,
                                            score, keys, ghist, i);
        }

        k_collect<<<32, 1024, 0, stream>>>(keys, ghist, selbuf, ckey, cidx, degN, n, k);
        k_rank   <<<1, 1024, 0, stream>>>(ckey, cidx, selbuf, cursor);
        k_compact<<<64, 256, 0, stream>>>(keys, selbuf, cursor, remap, keep_ids, n);

        k_pool<<<PBLK + EBLK, 256, 0, stream>>>(AGG, score, keep_ids, remap, H, rbuf,
                                                esrcP, edstP, esrcN, edstN,
                                                &ecnt[i], &ecnt[i+1], degN, k, i);
    }

    k_lin1<<<LIN1B, 320, 0, stream>>>(rbuf, w1, z1part);
    k_lin2<<<1, 320, 0, stream>>>(z1part, b1, w2, b2, prelua, out);
}

// Round 5
// 2984.347 us; speedup vs baseline: 22.9780x; 22.9780x over previous
//
#include <hip/hip_runtime.h>
#include <hip/hip_bf16.h>

#define NEDGE 640000
#define NMAX  40000
#define SB    40      // scan blocks
#define PBLK  256     // pool blocks
#define EBLK  320     // edge-compact blocks
#define FB    1280    // fill blocks (128 thr each)
#define LIN1B 64      // lin1 partial blocks
#define GRB   32      // gemm rows per block

// ---------------------------------------------------------------- helpers
__device__ inline void atomicMaxF(float* addr, float val) {
    unsigned* ua = (unsigned*)addr;
    unsigned old = *ua;
    while (__uint_as_float(old) < val) {
        unsigned assumed = old;
        old = atomicCAS(ua, assumed, __float_as_uint(val));
        if (old == assumed) break;
    }
}

__device__ inline unsigned orderKey(float s) {
    unsigned b = __float_as_uint(s);
    return (b & 0x80000000u) ? ~b : (b | 0x80000000u);
}

// ballot-dedup LDS histogram insert: O(1) atomics per distinct bin per wave
// (robust to total degeneracy — all lanes same bin costs 1 atomic)
__device__ inline void histAdd(int* sh, int bin, bool act, int nbits) {
    unsigned long long mm = __ballot(act);
    for (int b = 0; b < nbits; b++) {
        unsigned long long bal = __ballot(act && ((bin >> b) & 1));
        mm &= ((bin >> b) & 1) ? bal : ~bal;
    }
    if (act) {
        int lane = threadIdx.x & 63;
        int leader = __ffsll(mm) - 1;
        if (lane == leader) atomicAdd(&sh[bin], __popcll(mm));
    }
}

__device__ const float c_invk[10] = {
    1.0f/32000.0f, 1.0f/25600.0f, 1.0f/20480.0f, 1.0f/16384.0f, 1.0f/13108.0f,
    1.0f/10487.0f, 1.0f/8390.0f,  1.0f/6712.0f,  1.0f/5370.0f,  1.0f/4296.0f };

// selbuf slots: 0=bstar 1=rem 2=candcnt 3=thresh 4=cut 5=slotcnt

// ---------------------------------------------------------------- init (+ layer-0 degree count)
__global__ void k_init(const int* __restrict__ eidx, int* __restrict__ esrc,
                       int* __restrict__ edst, const float* __restrict__ poolp,
                       float* __restrict__ rbuf, float* __restrict__ pnorm,
                       int* __restrict__ ecnt, int* __restrict__ degA) {
    int b = blockIdx.x, t = threadIdx.x;
    if (b < 10) {
        rbuf[b*256 + t] = (t < 128) ? -3.402823e38f : 0.0f;
        __shared__ float red[256];
        float v = 0.0f;
        if (t < 128) { float pv = poolp[b*128 + t]; v = pv*pv; }
        red[t] = v; __syncthreads();
        for (int s = 128; s > 0; s >>= 1) { if (t < s) red[t] += red[t+s]; __syncthreads(); }
        if (t == 0) pnorm[b] = sqrtf(red[0]);
    }
    if (b == 10 && t < 16) ecnt[t] = (t == 0) ? NEDGE : 0;
    int e = b*256 + t;
    if (e < NEDGE) {
        int d = eidx[NEDGE + e];
        esrc[e] = eidx[e]; edst[e] = d;
        atomicAdd(&degA[d], 1);
    }
}

// ---------------------------------------------------------------- scan pass 1 (+ per-layer zeroing)
__global__ void k_s1(const int* __restrict__ deg, int* __restrict__ bpart,
                     int* __restrict__ ghist, int* __restrict__ selbuf, int n, int chunk) {
    int b = blockIdx.x, t = threadIdx.x;
    if (b == 0) {
        for (int jj = t; jj < 2048; jj += 256) ghist[jj] = 0;
        if (t == 0) { selbuf[2] = 0; selbuf[5] = 0; }
    }
    int start = b*chunk, end = min(start + chunk, n);
    int s = 0;
    for (int i = start + t; i < end; i += 256) s += deg[i];
    __shared__ int red[256];
    red[t] = s; __syncthreads();
    for (int st = 128; st > 0; st >>= 1) { if (t < st) red[t] += red[t+st]; __syncthreads(); }
    if (t == 0) bpart[b] = red[0];
}

// ---------------------------------------------------------------- scan pass 2
__global__ void k_s3(const int* __restrict__ deg, const int* __restrict__ bpart,
                     int* __restrict__ offs, int* __restrict__ cursor,
                     float* __restrict__ dinv, int n, int chunk) {
    int b = blockIdx.x, t = threadIdx.x, lane = t & 63, wid = t >> 6;
    __shared__ int wsum[4];
    __shared__ int s_carry;
    if (t < 64) {
        int v = (lane < b) ? bpart[lane] : 0;
        for (int off = 32; off > 0; off >>= 1) v += __shfl_down(v, off);
        if (lane == 0) s_carry = v;
    }
    __syncthreads();
    int start = b*chunk, end = min(start + chunk, n);
    for (int base = start; base < end; base += 256) {
        int i = base + t;
        int d = (i < end) ? deg[i] : 0;
        int incl = d;
        for (int off = 1; off < 64; off <<= 1) {
            int o = __shfl_up(incl, off);
            if (lane >= off) incl += o;
        }
        if (lane == 63) wsum[wid] = incl;
        __syncthreads();
        if (t == 0) { int c = s_carry; for (int w = 0; w < 4; w++) { int tmp = wsum[w]; wsum[w] = c; c += tmp; } s_carry = c; }
        __syncthreads();
        int p = wsum[wid] + incl - d;
        if (i < end) {
            offs[i] = p; cursor[i] = p;
            dinv[i] = (d > 0) ? 1.0f/sqrtf((float)d) : 0.0f;
        }
        __syncthreads();
    }
}

// ---------------------------------------------------------------- fused CSR fill + GEMM
__global__ __launch_bounds__(128) void k_fillgemm(const int* __restrict__ esrc, const int* __restrict__ edst,
        int* __restrict__ cursor, int* __restrict__ csr, const int* __restrict__ ecnt,
        const float* __restrict__ h, const float* __restrict__ W, const float* __restrict__ V,
        const float* __restrict__ bias, float* __restrict__ HW, float* __restrict__ AGG, int n) {
    int b = blockIdx.x, t = threadIdx.x;
    __shared__ __align__(16) float ht[128*36];
    if (b < FB) {
        int ec = *ecnt;
        for (int e = b*128 + t; e < ec; e += FB*128) {
            int pos = atomicAdd(&cursor[edst[e]], 1);
            csr[pos] = esrc[e];
        }
        return;
    }
    int v0 = (b - FB) * GRB;
    for (int it = 0; it < GRB; it++) {
        ht[t*36 + it] = h[(v0 + it)*128 + t];
    }
    __syncthreads();
    float accW[GRB], accV[GRB];
    #pragma unroll
    for (int r = 0; r < GRB; r++) { accW[r] = 0.0f; accV[r] = 0.0f; }
    for (int k = 0; k < 128; k++) {
        float mw = W[k*128 + t];
        float mv = V[k*128 + t];
        const float* hp = &ht[k*36];
        #pragma unroll
        for (int r4 = 0; r4 < GRB; r4 += 4) {
            float4 hq = *(const float4*)(hp + r4);
            accW[r4+0] += hq.x*mw;  accV[r4+0] += hq.x*mv;
            accW[r4+1] += hq.y*mw;  accV[r4+1] += hq.y*mv;
            accW[r4+2] += hq.z*mw;  accV[r4+2] += hq.z*mv;
            accW[r4+3] += hq.w*mw;  accV[r4+3] += hq.w*mv;
        }
    }
    float bb = bias[t];
    for (int r = 0; r < GRB; r++) {
        int v = v0 + r;
        if (v >= n) break;
        HW[v*128 + t]  = accW[r];
        AGG[v*128 + t] = accV[r] + bb;
    }
}

// ---------------------------------------------------------------- layer-0 fused node update (+hist)
__global__ __launch_bounds__(128) void k_gather0(
    const float* __restrict__ x, const float* __restrict__ W1, const float* __restrict__ V1,
    const float* __restrict__ convb,
    const float* __restrict__ bng, const float* __restrict__ bnb,
    const float* __restrict__ bnm, const float* __restrict__ bnv,
    const float* __restrict__ poolp, const float* __restrict__ pnorm,
    const float* __restrict__ prelua,
    const int* __restrict__ offs, const int* __restrict__ deg, const float* __restrict__ dinv,
    const int* __restrict__ csr,
    float* __restrict__ AGG, float* __restrict__ score, unsigned* __restrict__ keys,
    int* __restrict__ ghist) {
    int v = blockIdx.x, j = threadIdx.x;
    __shared__ float red[128];
    int off = offs[v], dg = deg[v];
    float accs = 0.0f;
    for (int c = j; c < dg; c += 128) { int s = csr[off + c]; accs += x[s]*dinv[s]; }
    red[j] = accs; __syncthreads();
    for (int st = 64; st > 0; st >>= 1) { if (j < st) red[j] += red[j+st]; __syncthreads(); }
    float aggs = red[0] * dinv[v];
    __syncthreads();
    float h2 = aggs*W1[j] + x[v]*V1[j] + convb[j];
    h2 = fmaxf(h2, 0.0f);
    float scale = bng[j] / sqrtf(bnv[j] + 1e-5f);
    h2 = (h2 - bnm[j])*scale + bnb[j];
    float a = prelua[0];
    h2 = (h2 > 0.0f) ? h2 : a*h2;
    AGG[v*128 + j] = h2;
    red[j] = h2 * poolp[j]; __syncthreads();
    for (int st = 64; st > 0; st >>= 1) { if (j < st) red[j] += red[j+st]; __syncthreads(); }
    if (j == 0) {
        float sc = tanhf(red[0] / pnorm[0]);
        unsigned key = orderKey(sc);
        score[v] = sc;
        keys[v]  = key;
        atomicAdd(&ghist[key >> 21], 1);
    }
}

// ---------------------------------------------------------------- generic fused gather + update + score (+hist)
__global__ __launch_bounds__(128) void k_gather(
    const float* __restrict__ HW, float* __restrict__ AGG,
    const int* __restrict__ offs, const int* __restrict__ deg, const float* __restrict__ dinv,
    const int* __restrict__ csr,
    const float* __restrict__ bng, const float* __restrict__ bnb,
    const float* __restrict__ bnm, const float* __restrict__ bnv,
    const float* __restrict__ poolp, const float* __restrict__ pnorm,
    const float* __restrict__ prelua,
    float* __restrict__ score, unsigned* __restrict__ keys, int* __restrict__ ghist, int layer) {
    int v = blockIdx.x, j = threadIdx.x;
    __shared__ int   s_src[128];
    __shared__ float s_dv[128];
    __shared__ float red[128];
    int off = offs[v], dg = deg[v];
    float acc = 0.0f;
    for (int base = 0; base < dg; base += 128) {
        int cnt = min(128, dg - base);
        if (j < cnt) { int s = csr[off + base + j]; s_src[j] = s; s_dv[j] = dinv[s]; }
        __syncthreads();
        for (int c = 0; c < cnt; c++) acc += HW[s_src[c]*128 + j] * s_dv[c];
        __syncthreads();
    }
    int gj = layer*128 + j;
    float h2 = AGG[v*128 + j] + acc*dinv[v];
    h2 = fmaxf(h2, 0.0f);
    float scale = bng[gj] / sqrtf(bnv[gj] + 1e-5f);
    h2 = (h2 - bnm[gj])*scale + bnb[gj];
    float a = prelua[0];
    h2 = (h2 > 0.0f) ? h2 : a*h2;
    AGG[v*128 + j] = h2;
    red[j] = h2 * poolp[gj]; __syncthreads();
    for (int st = 64; st > 0; st >>= 1) { if (j < st) red[j] += red[j+st]; __syncthreads(); }
    if (j == 0) {
        float sc = tanhf(red[0] / pnorm[layer]);
        unsigned key = orderKey(sc);
        score[v] = sc;
        keys[v]  = key;
        atomicAdd(&ghist[key >> 21], 1);
    }
}

// ---------------------------------------------------------------- top-k stage 1: bin select + candidate collect (+degN zero)
__global__ __launch_bounds__(1024) void k_collect(const unsigned* __restrict__ keys,
                                                  const int* __restrict__ ghist,
                                                  int* __restrict__ selbuf,
                                                  unsigned* __restrict__ ckey, int* __restrict__ cidx,
                                                  int* __restrict__ degN, int n, int kk) {
    __shared__ int sh[2048];
    __shared__ int s_bstar, s_base, s_cur;
    __shared__ int red[1024];
    int t = threadIdx.x, lane = t & 63;
    for (int i = blockIdx.x*1024 + t; i < NMAX; i += gridDim.x*1024) degN[i] = 0;
    sh[t] = ghist[t]; sh[t+1024] = ghist[t+1024];
    __syncthreads();
    for (int off = 1; off < 2048; off <<= 1) {
        int v0 = sh[t]      + ((t+off < 2048)      ? sh[t+off]      : 0);
        int v1 = sh[t+1024] + ((t+1024+off < 2048) ? sh[t+1024+off] : 0);
        __syncthreads();
        sh[t] = v0; sh[t+1024] = v1;
        __syncthreads();
    }
    for (int d = t; d < 2048; d += 1024) {
        int S = sh[d], Sn = (d == 2047) ? 0 : sh[d+1];
        if (S >= kk && Sn < kk) {
            s_bstar = d;
            if (blockIdx.x == 0) { selbuf[0] = d; selbuf[1] = kk - Sn; }
        }
    }
    __syncthreads();
    int bstar = s_bstar;
    int cnt = 0;
    for (int i = blockIdx.x*1024 + t; i < n; i += gridDim.x*1024)
        cnt += ((int)(keys[i] >> 21) == bstar);
    red[t] = cnt; __syncthreads();
    for (int st = 512; st > 0; st >>= 1) { if (t < st) red[t] += red[t+st]; __syncthreads(); }
    if (t == 0) { s_base = atomicAdd(&selbuf[2], red[0]); s_cur = 0; }
    __syncthreads();
    for (int base = blockIdx.x*1024; base < n; base += gridDim.x*1024) {
        int i = base + t;
        bool keep = false; unsigned key = 0;
        if (i < n) { key = keys[i]; keep = ((int)(key >> 21) == bstar); }
        unsigned long long m = __ballot(keep);
        int wcnt = __popcll(m);
        int wbase = 0;
        if (lane == 0 && wcnt) wbase = atomicAdd(&s_cur, wcnt);
        wbase = __shfl(wbase, 0);
        if (keep) {
            int pos = s_base + wbase + __popcll(m & ((1ULL << lane) - 1));
            ckey[pos] = key; cidx[pos] = i;
        }
    }
}

// ---------------------------------------------------------------- top-k stage 2: O(m) refine
// exact 32-bit threshold (2 histogram passes) + tie index cutoff (2 byte passes).
// Robust to total key degeneracy (ballot-dedup histograms).
__global__ __launch_bounds__(1024) void k_refine2(const unsigned* __restrict__ ckey,
                                                  const int* __restrict__ cidx,
                                                  int* __restrict__ selbuf) {
    __shared__ int sh[2048];
    __shared__ int s_dA, s_remA, s_dB, s_ntk, s_bC, s_rem2, s_cut;
    int t = threadIdx.x;
    int m = selbuf[2], rem = selbuf[1];
    int mR = (m + 1023) & ~1023;

    // ---- pass A: key bits 20..10 (2048 bins), suffix-scan select
    sh[t] = 0; sh[t+1024] = 0;
    __syncthreads();
    for (int i = t; i < mR; i += 1024) {
        bool act = (i < m);
        int bin = act ? (int)((ckey[i] >> 10) & 2047) : 0;
        histAdd(sh, bin, act, 11);
    }
    __syncthreads();
    for (int off = 1; off < 2048; off <<= 1) {
        int v0 = sh[t]      + ((t+off < 2048)      ? sh[t+off]      : 0);
        int v1 = sh[t+1024] + ((t+1024+off < 2048) ? sh[t+1024+off] : 0);
        __syncthreads();
        sh[t] = v0; sh[t+1024] = v1;
        __syncthreads();
    }
    for (int d = t; d < 2048; d += 1024) {
        int S = sh[d], Sn = (d == 2047) ? 0 : sh[d+1];
        if (S >= rem && Sn < rem) { s_dA = d; s_remA = rem - Sn; }
    }
    __syncthreads();
    int dA = s_dA, remA = s_remA;

    // ---- pass B: key bits 9..0 (1024 bins)
    sh[t] = 0;
    __syncthreads();
    for (int i = t; i < mR; i += 1024) {
        bool act = (i < m) && ((int)((ckey[i] >> 10) & 2047) == dA);
        int bin = act ? (int)(ckey[i] & 1023) : 0;
        histAdd(sh, bin, act, 10);
    }
    __syncthreads();
    for (int off = 1; off < 1024; off <<= 1) {
        int v0 = sh[t] + ((t+off < 1024) ? sh[t+off] : 0);
        __syncthreads();
        sh[t] = v0;
        __syncthreads();
    }
    {
        int S = sh[t], Sn = (t == 1023) ? 0 : sh[t+1];
        if (S >= remA && Sn < remA) { s_dB = t; s_ntk = remA - Sn; }
    }
    __syncthreads();
    unsigned thresh = ((unsigned)selbuf[0] << 21) | ((unsigned)dA << 10) | (unsigned)s_dB;
    int ntk = s_ntk;

    // ---- pass C: tie index high byte (256 bins), ascending prefix select
    if (t < 256) sh[t] = 0;
    __syncthreads();
    for (int i = t; i < mR; i += 1024) {
        bool act = (i < m) && (ckey[i] == thresh);
        int bin = act ? (cidx[i] >> 8) : 0;
        histAdd(sh, bin, act, 8);
    }
    __syncthreads();
    for (int off = 1; off < 256; off <<= 1) {
        int v = 0;
        if (t < 256) v = sh[t] + ((t >= off) ? sh[t-off] : 0);
        __syncthreads();
        if (t < 256) sh[t] = v;
        __syncthreads();
    }
    if (t < 256) {
        int P = sh[t], Pp = (t == 0) ? 0 : sh[t-1];
        if (P >= ntk && Pp < ntk) { s_bC = t; s_rem2 = ntk - Pp; }
    }
    __syncthreads();
    int bC = s_bC, rem2 = s_rem2;

    // ---- pass D: tie index low byte among high-byte==bC
    if (t < 256) sh[t] = 0;
    __syncthreads();
    for (int i = t; i < mR; i += 1024) {
        bool act = (i < m) && (ckey[i] == thresh) && ((cidx[i] >> 8) == bC);
        int bin = act ? (cidx[i] & 255) : 0;
        histAdd(sh, bin, act, 8);
    }
    __syncthreads();
    for (int off = 1; off < 256; off <<= 1) {
        int v = 0;
        if (t < 256) v = sh[t] + ((t >= off) ? sh[t-off] : 0);
        __syncthreads();
        if (t < 256) sh[t] = v;
        __syncthreads();
    }
    if (t < 256) {
        int P = sh[t], Pp = (t == 0) ? 0 : sh[t-1];
        if (P >= rem2 && Pp < rem2) s_cut = (bC << 8) | t;
    }
    __syncthreads();
    if (t == 0) { selbuf[3] = (int)thresh; selbuf[4] = s_cut; selbuf[5] = 0; }
}

// ---------------------------------------------------------------- top-k stage 3: compaction (key/cut predicate)
__global__ void k_compact(const unsigned* __restrict__ keys, int* __restrict__ selbuf,
                          int* __restrict__ remap, int* __restrict__ keep_ids, int n) {
    unsigned thresh = (unsigned)selbuf[3];
    int cut = selbuf[4];
    int t = threadIdx.x, lane = t & 63;
    __shared__ int s_base, s_cur;
    __shared__ int red[256];
    int cnt = 0;
    for (int base = blockIdx.x*256; base < n; base += gridDim.x*256) {
        int i = base + t;
        if (i < n) {
            unsigned key = keys[i];
            cnt += (key > thresh) || (key == thresh && i <= cut);
        }
    }
    red[t] = cnt; __syncthreads();
    for (int st = 128; st > 0; st >>= 1) { if (t < st) red[t] += red[t+st]; __syncthreads(); }
    if (t == 0) { s_base = atomicAdd(&selbuf[5], red[0]); s_cur = 0; }
    __syncthreads();
    for (int base = blockIdx.x*256; base < n; base += gridDim.x*256) {
        int i = base + t;
        bool keep = false;
        if (i < n) {
            unsigned key = keys[i];
            keep = (key > thresh) || (key == thresh && i <= cut);
        }
        unsigned long long m = __ballot(keep);
        int wcnt = __popcll(m);
        int wbase = 0;
        if (lane == 0 && wcnt) wbase = atomicAdd(&s_cur, wcnt);
        wbase = __shfl(wbase, 0);
        if (keep) {
            int slot = s_base + wbase + __popcll(m & ((1ULL << lane) - 1));
            remap[i] = slot; keep_ids[slot] = i;
        } else if (i < n) remap[i] = -1;
    }
}

// ---------------------------------------------------------------- pool + edge remap/compact (+next-layer degree)
__global__ void k_pool(const float* __restrict__ AGG, const float* __restrict__ score,
                       const int* __restrict__ keep_ids, const int* __restrict__ remap,
                       float* __restrict__ H, float* __restrict__ rbuf,
                       const int* __restrict__ esrcP, const int* __restrict__ edstP,
                       int* __restrict__ esrcN, int* __restrict__ edstN,
                       const int* __restrict__ ecntP, int* __restrict__ ecntN,
                       int* __restrict__ degN, int k, int layer) {
    int b = blockIdx.x, t = threadIdx.x;
    if (b < PBLK) {
        int sub = t >> 7, j = t & 127;
        float lmax = -3.402823e38f, lsum = 0.0f;
        int s = b*2 + sub;
        int v = (s < k) ? keep_ids[s] : 0;
        while (s < k) {
            float sc = score[v];
            float val = AGG[v*128 + j] * sc;
            int s2 = s + PBLK*2;
            int v2 = (s2 < k) ? keep_ids[s2] : 0;
            H[s*128 + j] = val;
            lmax = fmaxf(lmax, val); lsum += val;
            s = s2; v = v2;
        }
        __shared__ float shm[256], shs[256];
        shm[t] = lmax; shs[t] = lsum;
        __syncthreads();
        if (sub == 0) {
            lmax = fmaxf(shm[j], shm[j+128]);
            lsum = shs[j] + shs[j+128];
            atomicMaxF(&rbuf[layer*256 + j], lmax);
            atomicAdd(&rbuf[layer*256 + 128 + j], lsum);
        }
    } else {
        int eb = b - PBLK, lane = t & 63;
        int ec = *ecntP;
        __shared__ int s_base, s_cur;
        __shared__ int red[256];
        int cnt = 0;
        for (int base = eb*256; base < ec; base += EBLK*256) {
            int e = base + t;
            if (e < ec) {
                int ns = remap[esrcP[e]], nd = remap[edstP[e]];
                cnt += (ns >= 0 && nd >= 0);
            }
        }
        red[t] = cnt; __syncthreads();
        for (int st = 128; st > 0; st >>= 1) { if (t < st) red[t] += red[t+st]; __syncthreads(); }
        if (t == 0) { s_base = atomicAdd(ecntN, red[0]); s_cur = 0; }
        __syncthreads();
        for (int base = eb*256; base < ec; base += EBLK*256) {
            int e = base + t;
            bool keep = false; int ns = 0, nd = 0;
            if (e < ec) {
                ns = remap[esrcP[e]]; nd = remap[edstP[e]];
                keep = (ns >= 0 && nd >= 0);
            }
            unsigned long long m = __ballot(keep);
            int wcnt = __popcll(m);
            int wbase = 0;
            if (lane == 0 && wcnt) wbase = atomicAdd(&s_cur, wcnt);
            wbase = __shfl(wbase, 0);
            if (keep) {
                int pos = s_base + wbase + __popcll(m & ((1ULL << lane) - 1));
                esrcN[pos] = ns; edstN[pos] = nd;
                atomicAdd(&degN[nd], 1);
            }
        }
    }
}

// ---------------------------------------------------------------- MLP head
__global__ __launch_bounds__(320) void k_lin1(const float* __restrict__ rbuf,
                                              const float* __restrict__ w1,
                                              float* __restrict__ z1part) {
    int b = blockIdx.x, t = threadIdx.x;
    int j = t*4;
    float4 acc = make_float4(0.f, 0.f, 0.f, 0.f);
    int i0 = b*40;
    for (int r = 0; r < 40; r++) {
        int i = i0 + r;
        float rv = rbuf[i];
        if (i & 128) rv *= c_invk[i >> 8];
        float4 w = *(const float4*)(w1 + (size_t)i*1280 + j);
        acc.x += rv*w.x; acc.y += rv*w.y; acc.z += rv*w.z; acc.w += rv*w.w;
    }
    *(float4*)(z1part + b*1280 + j) = acc;
}

__global__ __launch_bounds__(320) void k_lin2(const float* __restrict__ z1part,
                                              const float* __restrict__ b1,
                                              const float* __restrict__ w2, const float* __restrict__ b2,
                                              const float* __restrict__ prelua, float* __restrict__ out) {
    int t = threadIdx.x, lane = t & 63, wid = t >> 6;
    float a = prelua[0];
    int j = t*4;
    float4 acc = make_float4(0.f, 0.f, 0.f, 0.f);
    for (int p = 0; p < LIN1B; p++) {
        float4 v = *(const float4*)(z1part + p*1280 + j);
        acc.x += v.x; acc.y += v.y; acc.z += v.z; acc.w += v.w;
    }
    float4 bb = *(const float4*)(b1 + j);
    float z0 = acc.x + bb.x; z0 = z0 > 0.f ? z0 : a*z0;
    float z1 = acc.y + bb.y; z1 = z1 > 0.f ? z1 : a*z1;
    float z2 = acc.z + bb.z; z2 = z2 > 0.f ? z2 : a*z2;
    float z3 = acc.w + bb.w; z3 = z3 > 0.f ? z3 : a*z3;
    float s[8];
    #pragma unroll
    for (int o = 0; o < 8; o++)
        s[o] = z0*w2[(j+0)*8+o] + z1*w2[(j+1)*8+o] + z2*w2[(j+2)*8+o] + z3*w2[(j+3)*8+o];
    #pragma unroll
    for (int off = 32; off > 0; off >>= 1)
        #pragma unroll
        for (int o = 0; o < 8; o++) s[o] += __shfl_down(s[o], off);
    __shared__ float sred[5][8];
    if (lane == 0)
        for (int o = 0; o < 8; o++) sred[wid][o] = s[o];
    __syncthreads();
    if (t == 0) {
        float zo[8];
        for (int o = 0; o < 8; o++) {
            float z = sred[0][o]+sred[1][o]+sred[2][o]+sred[3][o]+sred[4][o] + b2[o];
            zo[o] = z > 0.f ? z : a*z;
        }
        float mn = zo[0];
        for (int o = 1; o < 8; o++) mn = fminf(mn, zo[o]);
        float v[8], mx = -3.402823e38f;
        for (int o = 0; o < 8; o++) { v[o] = zo[o] - mn; mx = fmaxf(mx, v[o]); }
        float sm = 0.f;
        for (int o = 0; o < 8; o++) { v[o] = v[o] / mx; sm += v[o]; }
        for (int o = 0; o < 8; o++) out[o] = v[o] / sm;
    }
}

// ---------------------------------------------------------------- launch
extern "C" void kernel_launch(void* const* d_in, const int* in_sizes, int n_in,
                              void* d_out, int out_size, void* d_ws, size_t ws_size,
                              hipStream_t stream) {
    const float* x      = (const float*)d_in[0];
    const int*   eidx   = (const int*)  d_in[1];
    const float* W1     = (const float*)d_in[2];
    const float* V1     = (const float*)d_in[3];
    const float* Ws     = (const float*)d_in[4];
    const float* Vs     = (const float*)d_in[5];
    const float* convb  = (const float*)d_in[6];
    const float* bng    = (const float*)d_in[7];
    const float* bnb    = (const float*)d_in[8];
    const float* bnm    = (const float*)d_in[9];
    const float* bnv    = (const float*)d_in[10];
    const float* poolp  = (const float*)d_in[11];
    const float* prelua = (const float*)d_in[12];
    const float* w1     = (const float*)d_in[13];
    const float* b1     = (const float*)d_in[14];
    const float* w2     = (const float*)d_in[15];
    const float* b2     = (const float*)d_in[16];
    float* out = (float*)d_out;

    float* wsf  = (float*)d_ws;
    float* H      = wsf;
    float* HW     = H     + (size_t)NMAX*128;
    float* AGG    = HW    + (size_t)NMAX*128;
    float* dinv   = AGG   + (size_t)NMAX*128;
    float* score  = dinv  + NMAX;
    float* rbuf   = score + NMAX;
    float* pnorm  = rbuf  + 2560;
    float* z1part = pnorm + 16;                  // LIN1B*1280
    unsigned* keys = (unsigned*)(z1part + LIN1B*1280);
    int* esrcA  = (int*)(keys + NMAX);
    int* edstA  = esrcA + NEDGE;
    int* esrcB  = edstA + NEDGE;
    int* edstB  = esrcB + NEDGE;
    int* csr    = edstB + NEDGE;
    int* degA   = csr   + NEDGE;
    int* degB   = degA  + NMAX;
    int* ghist  = degB  + NMAX;                  // 2048
    int* offs   = ghist + 2048;
    int* cursor = offs  + NMAX;
    int* remap  = cursor + NMAX;
    int* keep_ids = remap + NMAX;
    unsigned* ckey = (unsigned*)(keep_ids + NMAX);
    int* cidx   = (int*)(ckey + NMAX);
    int* bpart  = cidx  + NMAX;                  // 64
    int* ecnt   = bpart + 64;                    // 16
    int* selbuf = ecnt  + 16;                    // 16

    static const int NS[10] = {40000,32000,25600,20480,16384,13108,10487,8390,6712,5370};
    static const int KS[10] = {32000,25600,20480,16384,13108,10487,8390,6712,5370,4296};

    hipMemsetAsync(degA, 0, (size_t)NMAX*sizeof(int), stream);
    k_init<<<2500, 256, 0, stream>>>(eidx, esrcA, edstA, poolp, rbuf, pnorm, ecnt, degA);

    for (int i = 0; i < 10; i++) {
        int n = NS[i], k = KS[i];
        int chunk = (n + SB - 1) / SB;
        int* esrcP = (i & 1) ? esrcB : esrcA;
        int* edstP = (i & 1) ? edstB : edstA;
        int* esrcN = (i & 1) ? esrcA : esrcB;
        int* edstN = (i & 1) ? edstA : edstB;
        int* degP  = (i & 1) ? degB : degA;
        int* degN  = (i & 1) ? degA : degB;

        k_s1<<<SB, 256, 0, stream>>>(degP, bpart, ghist, selbuf, n, chunk);
        k_s3<<<SB, 256, 0, stream>>>(degP, bpart, offs, cursor, dinv, n, chunk);

        int gb = (i == 0) ? 0 : (n + GRB - 1) / GRB;
        k_fillgemm<<<FB + gb, 128, 0, stream>>>(esrcP, edstP, cursor, csr, &ecnt[i],
                                                H, (i == 0) ? W1 : Ws + (size_t)(i-1)*16384,
                                                (i == 0) ? V1 : Vs + (size_t)(i-1)*16384,
                                                convb + i*128, HW, AGG, n);

        if (i == 0) {
            k_gather0<<<n, 128, 0, stream>>>(x, W1, V1, convb,
                                             bng, bnb, bnm, bnv, poolp, pnorm, prelua,
                                             offs, degP, dinv, csr, AGG, score, keys, ghist);
        } else {
            k_gather<<<n, 128, 0, stream>>>(HW, AGG, offs, degP, dinv, csr,
                                            bng, bnb, bnm, bnv, poolp, pnorm, prelua,
                                            score, keys, ghist, i);
        }

        k_collect<<<32, 1024, 0, stream>>>(keys, ghist, selbuf, ckey, cidx, degN, n, k);
        k_refine2<<<1, 1024, 0, stream>>>(ckey, cidx, selbuf);
        k_compact<<<64, 256, 0, stream>>>(keys, selbuf, remap, keep_ids, n);

        k_pool<<<PBLK + EBLK, 256, 0, stream>>>(AGG, score, keep_ids, remap, H, rbuf,
                                                esrcP, edstP, esrcN, edstN,
                                                &ecnt[i], &ecnt[i+1], degN, k, i);
    }

    k_lin1<<<LIN1B, 320, 0, stream>>>(rbuf, w1, z1part);
    k_lin2<<<1, 320, 0, stream>>>(z1part, b1, w2, b2, prelua, out);
}

// Round 6
// 1617.636 us; speedup vs baseline: 42.3918x; 1.8449x over previous
//
#include <hip/hip_runtime.h>
#include <hip/hip_bf16.h>

#define NEDGE 640000
#define NMAX  40000
#define SB    40      // scan blocks
#define PBLK  256     // pool blocks
#define EBLK  320     // edge-compact blocks
#define FB    1280    // fill blocks (128 thr each)
#define LIN1B 64      // lin1 partial blocks
#define GRB   32      // gemm rows per block

// ---------------------------------------------------------------- helpers
__device__ inline void atomicMaxF(float* addr, float val) {
    unsigned* ua = (unsigned*)addr;
    unsigned old = *ua;
    while (__uint_as_float(old) < val) {
        unsigned assumed = old;
        old = atomicCAS(ua, assumed, __float_as_uint(val));
        if (old == assumed) break;
    }
}

__device__ inline unsigned orderKey(float s) {
    unsigned b = __float_as_uint(s);
    return (b & 0x80000000u) ? ~b : (b | 0x80000000u);
}

// ballot-dedup LDS histogram insert: O(1) atomics per distinct bin per wave
// (robust to total degeneracy — all lanes same bin costs 1 atomic)
__device__ inline void histAdd(int* sh, int bin, bool act, int nbits) {
    unsigned long long mm = __ballot(act);
    for (int b = 0; b < nbits; b++) {
        unsigned long long bal = __ballot(act && ((bin >> b) & 1));
        mm &= ((bin >> b) & 1) ? bal : ~bal;
    }
    if (act) {
        int lane = threadIdx.x & 63;
        int leader = __ffsll(mm) - 1;
        if (lane == leader) atomicAdd(&sh[bin], __popcll(mm));
    }
}

__device__ const float c_invk[10] = {
    1.0f/32000.0f, 1.0f/25600.0f, 1.0f/20480.0f, 1.0f/16384.0f, 1.0f/13108.0f,
    1.0f/10487.0f, 1.0f/8390.0f,  1.0f/6712.0f,  1.0f/5370.0f,  1.0f/4296.0f };

// selbuf slots: 0=bstar 1=rem 2=candcnt 3=thresh 4=cut 5=slotcnt

// ---------------------------------------------------------------- init (+ layer-0 degree count)
__global__ void k_init(const int* __restrict__ eidx, int* __restrict__ esrc,
                       int* __restrict__ edst, const float* __restrict__ poolp,
                       float* __restrict__ rbuf, float* __restrict__ pnorm,
                       int* __restrict__ ecnt, int* __restrict__ degA) {
    int b = blockIdx.x, t = threadIdx.x;
    if (b < 10) {
        rbuf[b*256 + t] = (t < 128) ? -3.402823e38f : 0.0f;
        __shared__ float red[256];
        float v = 0.0f;
        if (t < 128) { float pv = poolp[b*128 + t]; v = pv*pv; }
        red[t] = v; __syncthreads();
        for (int s = 128; s > 0; s >>= 1) { if (t < s) red[t] += red[t+s]; __syncthreads(); }
        if (t == 0) pnorm[b] = sqrtf(red[0]);
    }
    if (b == 10 && t < 16) ecnt[t] = (t == 0) ? NEDGE : 0;
    int e = b*256 + t;
    if (e < NEDGE) {
        int d = eidx[NEDGE + e];
        esrc[e] = eidx[e]; edst[e] = d;
        atomicAdd(&degA[d], 1);
    }
}

// ---------------------------------------------------------------- scan pass 1 (+ per-layer zeroing)
__global__ void k_s1(const int* __restrict__ deg, int* __restrict__ bpart,
                     int* __restrict__ ghist, int* __restrict__ selbuf, int n, int chunk) {
    int b = blockIdx.x, t = threadIdx.x;
    if (b == 0) {
        for (int jj = t; jj < 2048; jj += 256) ghist[jj] = 0;
        if (t == 0) { selbuf[2] = 0; selbuf[5] = 0; }
    }
    int start = b*chunk, end = min(start + chunk, n);
    int s = 0;
    for (int i = start + t; i < end; i += 256) s += deg[i];
    __shared__ int red[256];
    red[t] = s; __syncthreads();
    for (int st = 128; st > 0; st >>= 1) { if (t < st) red[t] += red[t+st]; __syncthreads(); }
    if (t == 0) bpart[b] = red[0];
}

// ---------------------------------------------------------------- scan pass 2
__global__ void k_s3(const int* __restrict__ deg, const int* __restrict__ bpart,
                     int* __restrict__ offs, int* __restrict__ cursor,
                     float* __restrict__ dinv, int n, int chunk) {
    int b = blockIdx.x, t = threadIdx.x, lane = t & 63, wid = t >> 6;
    __shared__ int wsum[4];
    __shared__ int s_carry;
    if (t < 64) {
        int v = (lane < b) ? bpart[lane] : 0;
        for (int off = 32; off > 0; off >>= 1) v += __shfl_down(v, off);
        if (lane == 0) s_carry = v;
    }
    __syncthreads();
    int start = b*chunk, end = min(start + chunk, n);
    for (int base = start; base < end; base += 256) {
        int i = base + t;
        int d = (i < end) ? deg[i] : 0;
        int incl = d;
        for (int off = 1; off < 64; off <<= 1) {
            int o = __shfl_up(incl, off);
            if (lane >= off) incl += o;
        }
        if (lane == 63) wsum[wid] = incl;
        __syncthreads();
        if (t == 0) { int c = s_carry; for (int w = 0; w < 4; w++) { int tmp = wsum[w]; wsum[w] = c; c += tmp; } s_carry = c; }
        __syncthreads();
        int p = wsum[wid] + incl - d;
        if (i < end) {
            offs[i] = p; cursor[i] = p;
            dinv[i] = (d > 0) ? 1.0f/sqrtf((float)d) : 0.0f;
        }
        __syncthreads();
    }
}

// ---------------------------------------------------------------- fused CSR fill + GEMM
__global__ __launch_bounds__(128) void k_fillgemm(const int* __restrict__ esrc, const int* __restrict__ edst,
        int* __restrict__ cursor, int* __restrict__ csr, const int* __restrict__ ecnt,
        const float* __restrict__ h, const float* __restrict__ W, const float* __restrict__ V,
        const float* __restrict__ bias, float* __restrict__ HW, float* __restrict__ AGG, int n) {
    int b = blockIdx.x, t = threadIdx.x;
    __shared__ __align__(16) float ht[128*36];
    if (b < FB) {
        int ec = *ecnt;
        for (int e = b*128 + t; e < ec; e += FB*128) {
            int pos = atomicAdd(&cursor[edst[e]], 1);
            csr[pos] = esrc[e];
        }
        return;
    }
    int v0 = (b - FB) * GRB;
    for (int it = 0; it < GRB; it++) {
        ht[t*36 + it] = h[(v0 + it)*128 + t];
    }
    __syncthreads();
    float accW[GRB], accV[GRB];
    #pragma unroll
    for (int r = 0; r < GRB; r++) { accW[r] = 0.0f; accV[r] = 0.0f; }
    for (int k = 0; k < 128; k++) {
        float mw = W[k*128 + t];
        float mv = V[k*128 + t];
        const float* hp = &ht[k*36];
        #pragma unroll
        for (int r4 = 0; r4 < GRB; r4 += 4) {
            float4 hq = *(const float4*)(hp + r4);
            accW[r4+0] += hq.x*mw;  accV[r4+0] += hq.x*mv;
            accW[r4+1] += hq.y*mw;  accV[r4+1] += hq.y*mv;
            accW[r4+2] += hq.z*mw;  accV[r4+2] += hq.z*mv;
            accW[r4+3] += hq.w*mw;  accV[r4+3] += hq.w*mv;
        }
    }
    float bb = bias[t];
    for (int r = 0; r < GRB; r++) {
        int v = v0 + r;
        if (v >= n) break;
        HW[v*128 + t]  = accW[r];
        AGG[v*128 + t] = accV[r] + bb;
    }
}

// ---------------------------------------------------------------- layer-0 fused node update
__global__ __launch_bounds__(128) void k_gather0(
    const float* __restrict__ x, const float* __restrict__ W1, const float* __restrict__ V1,
    const float* __restrict__ convb,
    const float* __restrict__ bng, const float* __restrict__ bnb,
    const float* __restrict__ bnm, const float* __restrict__ bnv,
    const float* __restrict__ poolp, const float* __restrict__ pnorm,
    const float* __restrict__ prelua,
    const int* __restrict__ offs, const int* __restrict__ deg, const float* __restrict__ dinv,
    const int* __restrict__ csr,
    float* __restrict__ AGG, float* __restrict__ score, unsigned* __restrict__ keys) {
    int v = blockIdx.x, j = threadIdx.x;
    __shared__ float red[128];
    int off = offs[v], dg = deg[v];
    float accs = 0.0f;
    for (int c = j; c < dg; c += 128) { int s = csr[off + c]; accs += x[s]*dinv[s]; }
    red[j] = accs; __syncthreads();
    for (int st = 64; st > 0; st >>= 1) { if (j < st) red[j] += red[j+st]; __syncthreads(); }
    float aggs = red[0] * dinv[v];
    __syncthreads();
    float h2 = aggs*W1[j] + x[v]*V1[j] + convb[j];
    h2 = fmaxf(h2, 0.0f);
    float scale = bng[j] / sqrtf(bnv[j] + 1e-5f);
    h2 = (h2 - bnm[j])*scale + bnb[j];
    float a = prelua[0];
    h2 = (h2 > 0.0f) ? h2 : a*h2;
    AGG[v*128 + j] = h2;
    red[j] = h2 * poolp[j]; __syncthreads();
    for (int st = 64; st > 0; st >>= 1) { if (j < st) red[j] += red[j+st]; __syncthreads(); }
    if (j == 0) {
        float sc = tanhf(red[0] / pnorm[0]);
        score[v] = sc;
        keys[v]  = orderKey(sc);
    }
}

// ---------------------------------------------------------------- generic fused gather + update + score
__global__ __launch_bounds__(128) void k_gather(
    const float* __restrict__ HW, float* __restrict__ AGG,
    const int* __restrict__ offs, const int* __restrict__ deg, const float* __restrict__ dinv,
    const int* __restrict__ csr,
    const float* __restrict__ bng, const float* __restrict__ bnb,
    const float* __restrict__ bnm, const float* __restrict__ bnv,
    const float* __restrict__ poolp, const float* __restrict__ pnorm,
    const float* __restrict__ prelua,
    float* __restrict__ score, unsigned* __restrict__ keys, int layer) {
    int v = blockIdx.x, j = threadIdx.x;
    __shared__ int   s_src[128];
    __shared__ float s_dv[128];
    __shared__ float red[128];
    int off = offs[v], dg = deg[v];
    float acc = 0.0f;
    for (int base = 0; base < dg; base += 128) {
        int cnt = min(128, dg - base);
        if (j < cnt) { int s = csr[off + base + j]; s_src[j] = s; s_dv[j] = dinv[s]; }
        __syncthreads();
        for (int c = 0; c < cnt; c++) acc += HW[s_src[c]*128 + j] * s_dv[c];
        __syncthreads();
    }
    int gj = layer*128 + j;
    float h2 = AGG[v*128 + j] + acc*dinv[v];
    h2 = fmaxf(h2, 0.0f);
    float scale = bng[gj] / sqrtf(bnv[gj] + 1e-5f);
    h2 = (h2 - bnm[gj])*scale + bnb[gj];
    float a = prelua[0];
    h2 = (h2 > 0.0f) ? h2 : a*h2;
    AGG[v*128 + j] = h2;
    red[j] = h2 * poolp[gj]; __syncthreads();
    for (int st = 64; st > 0; st >>= 1) { if (j < st) red[j] += red[j+st]; __syncthreads(); }
    if (j == 0) {
        float sc = tanhf(red[0] / pnorm[layer]);
        score[v] = sc;
        keys[v]  = orderKey(sc);
    }
}

// ---------------------------------------------------------------- key histogram (ballot-dedup, degeneracy-safe)
__global__ void k_hist(const unsigned* __restrict__ keys, int* __restrict__ ghist, int n) {
    __shared__ int lh[2048];
    int t = threadIdx.x;
    for (int jj = t; jj < 2048; jj += 256) lh[jj] = 0;
    __syncthreads();
    int nR = (n + 255) & ~255;
    for (int i = blockIdx.x*256 + t; i < nR; i += gridDim.x*256) {
        bool act = (i < n);
        int bin = act ? (int)(keys[i] >> 21) : 0;
        histAdd(lh, bin, act, 11);
    }
    __syncthreads();
    for (int jj = t; jj < 2048; jj += 256) { int c = lh[jj]; if (c) atomicAdd(&ghist[jj], c); }
}

// ---------------------------------------------------------------- top-k stage 1: bin select + candidate collect (+degN zero)
__global__ __launch_bounds__(1024) void k_collect(const unsigned* __restrict__ keys,
                                                  const int* __restrict__ ghist,
                                                  int* __restrict__ selbuf,
                                                  unsigned* __restrict__ ckey, int* __restrict__ cidx,
                                                  int* __restrict__ degN, int n, int kk) {
    __shared__ int sh[2048];
    __shared__ int s_bstar, s_base, s_cur;
    __shared__ int red[1024];
    int t = threadIdx.x, lane = t & 63;
    for (int i = blockIdx.x*1024 + t; i < NMAX; i += gridDim.x*1024) degN[i] = 0;
    sh[t] = ghist[t]; sh[t+1024] = ghist[t+1024];
    __syncthreads();
    for (int off = 1; off < 2048; off <<= 1) {
        int v0 = sh[t]      + ((t+off < 2048)      ? sh[t+off]      : 0);
        int v1 = sh[t+1024] + ((t+1024+off < 2048) ? sh[t+1024+off] : 0);
        __syncthreads();
        sh[t] = v0; sh[t+1024] = v1;
        __syncthreads();
    }
    for (int d = t; d < 2048; d += 1024) {
        int S = sh[d], Sn = (d == 2047) ? 0 : sh[d+1];
        if (S >= kk && Sn < kk) {
            s_bstar = d;
            if (blockIdx.x == 0) { selbuf[0] = d; selbuf[1] = kk - Sn; }
        }
    }
    __syncthreads();
    int bstar = s_bstar;
    int cnt = 0;
    for (int i = blockIdx.x*1024 + t; i < n; i += gridDim.x*1024)
        cnt += ((int)(keys[i] >> 21) == bstar);
    red[t] = cnt; __syncthreads();
    for (int st = 512; st > 0; st >>= 1) { if (t < st) red[t] += red[t+st]; __syncthreads(); }
    if (t == 0) { s_base = atomicAdd(&selbuf[2], red[0]); s_cur = 0; }
    __syncthreads();
    for (int base = blockIdx.x*1024; base < n; base += gridDim.x*1024) {
        int i = base + t;
        bool keep = false; unsigned key = 0;
        if (i < n) { key = keys[i]; keep = ((int)(key >> 21) == bstar); }
        unsigned long long m = __ballot(keep);
        int wcnt = __popcll(m);
        int wbase = 0;
        if (lane == 0 && wcnt) wbase = atomicAdd(&s_cur, wcnt);
        wbase = __shfl(wbase, 0);
        if (keep) {
            int pos = s_base + wbase + __popcll(m & ((1ULL << lane) - 1));
            ckey[pos] = key; cidx[pos] = i;
        }
    }
}

// ---------------------------------------------------------------- top-k stage 2: O(m) refine
__global__ __launch_bounds__(1024) void k_refine2(const unsigned* __restrict__ ckey,
                                                  const int* __restrict__ cidx,
                                                  int* __restrict__ selbuf) {
    __shared__ int sh[2048];
    __shared__ int s_dA, s_remA, s_dB, s_ntk, s_bC, s_rem2, s_cut;
    int t = threadIdx.x;
    int m = selbuf[2], rem = selbuf[1];
    int mR = (m + 1023) & ~1023;

    // ---- pass A: key bits 20..10 (2048 bins), suffix-scan select
    sh[t] = 0; sh[t+1024] = 0;
    __syncthreads();
    for (int i = t; i < mR; i += 1024) {
        bool act = (i < m);
        int bin = act ? (int)((ckey[i] >> 10) & 2047) : 0;
        histAdd(sh, bin, act, 11);
    }
    __syncthreads();
    for (int off = 1; off < 2048; off <<= 1) {
        int v0 = sh[t]      + ((t+off < 2048)      ? sh[t+off]      : 0);
        int v1 = sh[t+1024] + ((t+1024+off < 2048) ? sh[t+1024+off] : 0);
        __syncthreads();
        sh[t] = v0; sh[t+1024] = v1;
        __syncthreads();
    }
    for (int d = t; d < 2048; d += 1024) {
        int S = sh[d], Sn = (d == 2047) ? 0 : sh[d+1];
        if (S >= rem && Sn < rem) { s_dA = d; s_remA = rem - Sn; }
    }
    __syncthreads();
    int dA = s_dA, remA = s_remA;

    // ---- pass B: key bits 9..0 (1024 bins)
    sh[t] = 0;
    __syncthreads();
    for (int i = t; i < mR; i += 1024) {
        bool act = (i < m) && ((int)((ckey[i] >> 10) & 2047) == dA);
        int bin = act ? (int)(ckey[i] & 1023) : 0;
        histAdd(sh, bin, act, 10);
    }
    __syncthreads();
    for (int off = 1; off < 1024; off <<= 1) {
        int v0 = sh[t] + ((t+off < 1024) ? sh[t+off] : 0);
        __syncthreads();
        sh[t] = v0;
        __syncthreads();
    }
    {
        int S = sh[t], Sn = (t == 1023) ? 0 : sh[t+1];
        if (S >= remA && Sn < remA) { s_dB = t; s_ntk = remA - Sn; }
    }
    __syncthreads();
    unsigned thresh = ((unsigned)selbuf[0] << 21) | ((unsigned)dA << 10) | (unsigned)s_dB;
    int ntk = s_ntk;

    // ---- pass C: tie index high byte (256 bins), ascending prefix select
    if (t < 256) sh[t] = 0;
    __syncthreads();
    for (int i = t; i < mR; i += 1024) {
        bool act = (i < m) && (ckey[i] == thresh);
        int bin = act ? (cidx[i] >> 8) : 0;
        histAdd(sh, bin, act, 8);
    }
    __syncthreads();
    for (int off = 1; off < 256; off <<= 1) {
        int v = 0;
        if (t < 256) v = sh[t] + ((t >= off) ? sh[t-off] : 0);
        __syncthreads();
        if (t < 256) sh[t] = v;
        __syncthreads();
    }
    if (t < 256) {
        int P = sh[t], Pp = (t == 0) ? 0 : sh[t-1];
        if (P >= ntk && Pp < ntk) { s_bC = t; s_rem2 = ntk - Pp; }
    }
    __syncthreads();
    int bC = s_bC, rem2 = s_rem2;

    // ---- pass D: tie index low byte among high-byte==bC
    if (t < 256) sh[t] = 0;
    __syncthreads();
    for (int i = t; i < mR; i += 1024) {
        bool act = (i < m) && (ckey[i] == thresh) && ((cidx[i] >> 8) == bC);
        int bin = act ? (cidx[i] & 255) : 0;
        histAdd(sh, bin, act, 8);
    }
    __syncthreads();
    for (int off = 1; off < 256; off <<= 1) {
        int v = 0;
        if (t < 256) v = sh[t] + ((t >= off) ? sh[t-off] : 0);
        __syncthreads();
        if (t < 256) sh[t] = v;
        __syncthreads();
    }
    if (t < 256) {
        int P = sh[t], Pp = (t == 0) ? 0 : sh[t-1];
        if (P >= rem2 && Pp < rem2) s_cut = (bC << 8) | t;
    }
    __syncthreads();
    if (t == 0) { selbuf[3] = (int)thresh; selbuf[4] = s_cut; selbuf[5] = 0; }
}

// ---------------------------------------------------------------- top-k stage 3: compaction
__global__ void k_compact(const unsigned* __restrict__ keys, int* __restrict__ selbuf,
                          int* __restrict__ remap, int* __restrict__ keep_ids, int n) {
    unsigned thresh = (unsigned)selbuf[3];
    int cut = selbuf[4];
    int t = threadIdx.x, lane = t & 63;
    __shared__ int s_base, s_cur;
    __shared__ int red[256];
    int cnt = 0;
    for (int base = blockIdx.x*256; base < n; base += gridDim.x*256) {
        int i = base + t;
        if (i < n) {
            unsigned key = keys[i];
            cnt += (key > thresh) || (key == thresh && i <= cut);
        }
    }
    red[t] = cnt; __syncthreads();
    for (int st = 128; st > 0; st >>= 1) { if (t < st) red[t] += red[t+st]; __syncthreads(); }
    if (t == 0) { s_base = atomicAdd(&selbuf[5], red[0]); s_cur = 0; }
    __syncthreads();
    for (int base = blockIdx.x*256; base < n; base += gridDim.x*256) {
        int i = base + t;
        bool keep = false;
        if (i < n) {
            unsigned key = keys[i];
            keep = (key > thresh) || (key == thresh && i <= cut);
        }
        unsigned long long m = __ballot(keep);
        int wcnt = __popcll(m);
        int wbase = 0;
        if (lane == 0 && wcnt) wbase = atomicAdd(&s_cur, wcnt);
        wbase = __shfl(wbase, 0);
        if (keep) {
            int slot = s_base + wbase + __popcll(m & ((1ULL << lane) - 1));
            remap[i] = slot; keep_ids[slot] = i;
        } else if (i < n) remap[i] = -1;
    }
}

// ---------------------------------------------------------------- pool + edge remap/compact (+next-layer degree)
__global__ void k_pool(const float* __restrict__ AGG, const float* __restrict__ score,
                       const int* __restrict__ keep_ids, const int* __restrict__ remap,
                       float* __restrict__ H, float* __restrict__ rbuf,
                       const int* __restrict__ esrcP, const int* __restrict__ edstP,
                       int* __restrict__ esrcN, int* __restrict__ edstN,
                       const int* __restrict__ ecntP, int* __restrict__ ecntN,
                       int* __restrict__ degN, int k, int layer) {
    int b = blockIdx.x, t = threadIdx.x;
    if (b < PBLK) {
        int sub = t >> 7, j = t & 127;
        float lmax = -3.402823e38f, lsum = 0.0f;
        int s = b*2 + sub;
        int v = (s < k) ? keep_ids[s] : 0;
        while (s < k) {
            float sc = score[v];
            float val = AGG[v*128 + j] * sc;
            int s2 = s + PBLK*2;
            int v2 = (s2 < k) ? keep_ids[s2] : 0;
            H[s*128 + j] = val;
            lmax = fmaxf(lmax, val); lsum += val;
            s = s2; v = v2;
        }
        __shared__ float shm[256], shs[256];
        shm[t] = lmax; shs[t] = lsum;
        __syncthreads();
        if (sub == 0) {
            lmax = fmaxf(shm[j], shm[j+128]);
            lsum = shs[j] + shs[j+128];
            atomicMaxF(&rbuf[layer*256 + j], lmax);
            atomicAdd(&rbuf[layer*256 + 128 + j], lsum);
        }
    } else {
        int eb = b - PBLK, lane = t & 63;
        int ec = *ecntP;
        __shared__ int s_base, s_cur;
        __shared__ int red[256];
        int cnt = 0;
        for (int base = eb*256; base < ec; base += EBLK*256) {
            int e = base + t;
            if (e < ec) {
                int ns = remap[esrcP[e]], nd = remap[edstP[e]];
                cnt += (ns >= 0 && nd >= 0);
            }
        }
        red[t] = cnt; __syncthreads();
        for (int st = 128; st > 0; st >>= 1) { if (t < st) red[t] += red[t+st]; __syncthreads(); }
        if (t == 0) { s_base = atomicAdd(ecntN, red[0]); s_cur = 0; }
        __syncthreads();
        for (int base = eb*256; base < ec; base += EBLK*256) {
            int e = base + t;
            bool keep = false; int ns = 0, nd = 0;
            if (e < ec) {
                ns = remap[esrcP[e]]; nd = remap[edstP[e]];
                keep = (ns >= 0 && nd >= 0);
            }
            unsigned long long m = __ballot(keep);
            int wcnt = __popcll(m);
            int wbase = 0;
            if (lane == 0 && wcnt) wbase = atomicAdd(&s_cur, wcnt);
            wbase = __shfl(wbase, 0);
            if (keep) {
                int pos = s_base + wbase + __popcll(m & ((1ULL << lane) - 1));
                esrcN[pos] = ns; edstN[pos] = nd;
                atomicAdd(&degN[nd], 1);
            }
        }
    }
}

// ---------------------------------------------------------------- MLP head
__global__ __launch_bounds__(320) void k_lin1(const float* __restrict__ rbuf,
                                              const float* __restrict__ w1,
                                              float* __restrict__ z1part) {
    int b = blockIdx.x, t = threadIdx.x;
    int j = t*4;
    float4 acc = make_float4(0.f, 0.f, 0.f, 0.f);
    int i0 = b*40;
    for (int r = 0; r < 40; r++) {
        int i = i0 + r;
        float rv = rbuf[i];
        if (i & 128) rv *= c_invk[i >> 8];
        float4 w = *(const float4*)(w1 + (size_t)i*1280 + j);
        acc.x += rv*w.x; acc.y += rv*w.y; acc.z += rv*w.z; acc.w += rv*w.w;
    }
    *(float4*)(z1part + b*1280 + j) = acc;
}

__global__ __launch_bounds__(320) void k_lin2(const float* __restrict__ z1part,
                                              const float* __restrict__ b1,
                                              const float* __restrict__ w2, const float* __restrict__ b2,
                                              const float* __restrict__ prelua, float* __restrict__ out) {
    int t = threadIdx.x, lane = t & 63, wid = t >> 6;
    float a = prelua[0];
    int j = t*4;
    float4 acc = make_float4(0.f, 0.f, 0.f, 0.f);
    for (int p = 0; p < LIN1B; p++) {
        float4 v = *(const float4*)(z1part + p*1280 + j);
        acc.x += v.x; acc.y += v.y; acc.z += v.z; acc.w += v.w;
    }
    float4 bb = *(const float4*)(b1 + j);
    float z0 = acc.x + bb.x; z0 = z0 > 0.f ? z0 : a*z0;
    float z1 = acc.y + bb.y; z1 = z1 > 0.f ? z1 : a*z1;
    float z2 = acc.z + bb.z; z2 = z2 > 0.f ? z2 : a*z2;
    float z3 = acc.w + bb.w; z3 = z3 > 0.f ? z3 : a*z3;
    float s[8];
    #pragma unroll
    for (int o = 0; o < 8; o++)
        s[o] = z0*w2[(j+0)*8+o] + z1*w2[(j+1)*8+o] + z2*w2[(j+2)*8+o] + z3*w2[(j+3)*8+o];
    #pragma unroll
    for (int off = 32; off > 0; off >>= 1)
        #pragma unroll
        for (int o = 0; o < 8; o++) s[o] += __shfl_down(s[o], off);
    __shared__ float sred[5][8];
    if (lane == 0)
        for (int o = 0; o < 8; o++) sred[wid][o] = s[o];
    __syncthreads();
    if (t == 0) {
        float zo[8];
        for (int o = 0; o < 8; o++) {
            float z = sred[0][o]+sred[1][o]+sred[2][o]+sred[3][o]+sred[4][o] + b2[o];
            zo[o] = z > 0.f ? z : a*z;
        }
        float mn = zo[0];
        for (int o = 1; o < 8; o++) mn = fminf(mn, zo[o]);
        float v[8], mx = -3.402823e38f;
        for (int o = 0; o < 8; o++) { v[o] = zo[o] - mn; mx = fmaxf(mx, v[o]); }
        float sm = 0.f;
        for (int o = 0; o < 8; o++) { v[o] = v[o] / mx; sm += v[o]; }
        for (int o = 0; o < 8; o++) out[o] = v[o] / sm;
    }
}

// ---------------------------------------------------------------- launch
extern "C" void kernel_launch(void* const* d_in, const int* in_sizes, int n_in,
                              void* d_out, int out_size, void* d_ws, size_t ws_size,
                              hipStream_t stream) {
    const float* x      = (const float*)d_in[0];
    const int*   eidx   = (const int*)  d_in[1];
    const float* W1     = (const float*)d_in[2];
    const float* V1     = (const float*)d_in[3];
    const float* Ws     = (const float*)d_in[4];
    const float* Vs     = (const float*)d_in[5];
    const float* convb  = (const float*)d_in[6];
    const float* bng    = (const float*)d_in[7];
    const float* bnb    = (const float*)d_in[8];
    const float* bnm    = (const float*)d_in[9];
    const float* bnv    = (const float*)d_in[10];
    const float* poolp  = (const float*)d_in[11];
    const float* prelua = (const float*)d_in[12];
    const float* w1     = (const float*)d_in[13];
    const float* b1     = (const float*)d_in[14];
    const float* w2     = (const float*)d_in[15];
    const float* b2     = (const float*)d_in[16];
    float* out = (float*)d_out;

    float* wsf  = (float*)d_ws;
    float* H      = wsf;
    float* HW     = H     + (size_t)NMAX*128;
    float* AGG    = HW    + (size_t)NMAX*128;
    float* dinv   = AGG   + (size_t)NMAX*128;
    float* score  = dinv  + NMAX;
    float* rbuf   = score + NMAX;
    float* pnorm  = rbuf  + 2560;
    float* z1part = pnorm + 16;                  // LIN1B*1280
    unsigned* keys = (unsigned*)(z1part + LIN1B*1280);
    int* esrcA  = (int*)(keys + NMAX);
    int* edstA  = esrcA + NEDGE;
    int* esrcB  = edstA + NEDGE;
    int* edstB  = esrcB + NEDGE;
    int* csr    = edstB + NEDGE;
    int* degA   = csr   + NEDGE;
    int* degB   = degA  + NMAX;
    int* ghist  = degB  + NMAX;                  // 2048
    int* offs   = ghist + 2048;
    int* cursor = offs  + NMAX;
    int* remap  = cursor + NMAX;
    int* keep_ids = remap + NMAX;
    unsigned* ckey = (unsigned*)(keep_ids + NMAX);
    int* cidx   = (int*)(ckey + NMAX);
    int* bpart  = cidx  + NMAX;                  // 64
    int* ecnt   = bpart + 64;                    // 16
    int* selbuf = ecnt  + 16;                    // 16

    static const int NS[10] = {40000,32000,25600,20480,16384,13108,10487,8390,6712,5370};
    static const int KS[10] = {32000,25600,20480,16384,13108,10487,8390,6712,5370,4296};

    hipMemsetAsync(degA, 0, (size_t)NMAX*sizeof(int), stream);
    k_init<<<2500, 256, 0, stream>>>(eidx, esrcA, edstA, poolp, rbuf, pnorm, ecnt, degA);

    for (int i = 0; i < 10; i++) {
        int n = NS[i], k = KS[i];
        int chunk = (n + SB - 1) / SB;
        int* esrcP = (i & 1) ? esrcB : esrcA;
        int* edstP = (i & 1) ? edstB : edstA;
        int* esrcN = (i & 1) ? esrcA : esrcB;
        int* edstN = (i & 1) ? edstA : edstB;
        int* degP  = (i & 1) ? degB : degA;
        int* degN  = (i & 1) ? degA : degB;

        k_s1<<<SB, 256, 0, stream>>>(degP, bpart, ghist, selbuf, n, chunk);
        k_s3<<<SB, 256, 0, stream>>>(degP, bpart, offs, cursor, dinv, n, chunk);

        int gb = (i == 0) ? 0 : (n + GRB - 1) / GRB;
        k_fillgemm<<<FB + gb, 128, 0, stream>>>(esrcP, edstP, cursor, csr, &ecnt[i],
                                                H, (i == 0) ? W1 : Ws + (size_t)(i-1)*16384,
                                                (i == 0) ? V1 : Vs + (size_t)(i-1)*16384,
                                                convb + i*128, HW, AGG, n);

        if (i == 0) {
            k_gather0<<<n, 128, 0, stream>>>(x, W1, V1, convb,
                                             bng, bnb, bnm, bnv, poolp, pnorm, prelua,
                                             offs, degP, dinv, csr, AGG, score, keys);
        } else {
            k_gather<<<n, 128, 0, stream>>>(HW, AGG, offs, degP, dinv, csr,
                                            bng, bnb, bnm, bnv, poolp, pnorm, prelua,
                                            score, keys, i);
        }

        k_hist   <<<32, 256, 0, stream>>>(keys, ghist, n);
        k_collect<<<32, 1024, 0, stream>>>(keys, ghist, selbuf, ckey, cidx, degN, n, k);
        k_refine2<<<1, 1024, 0, stream>>>(ckey, cidx, selbuf);
        k_compact<<<64, 256, 0, stream>>>(keys, selbuf, remap, keep_ids, n);

        k_pool<<<PBLK + EBLK, 256, 0, stream>>>(AGG, score, keep_ids, remap, H, rbuf,
                                                esrcP, edstP, esrcN, edstN,
                                                &ecnt[i], &ecnt[i+1], degN, k, i);
    }

    k_lin1<<<LIN1B, 320, 0, stream>>>(rbuf, w1, z1part);
    k_lin2<<<1, 320, 0, stream>>>(z1part, b1, w2, b2, prelua, out);
}

// Round 7
// 1616.888 us; speedup vs baseline: 42.4114x; 1.0005x over previous
//
#include <hip/hip_runtime.h>
#include <hip/hip_bf16.h>

#define NEDGE 640000
#define NMAX  40000
#define SB    40      // scan blocks
#define PBLK  256     // pool blocks
#define EBLK  320     // edge-compact blocks
#define FB    1280    // fill blocks (128 thr each)
#define LIN1B 64      // lin1 partial blocks
#define GRB   32      // gemm rows per block
#define KT    16      // gemm K-tile

// ---------------------------------------------------------------- helpers
__device__ inline void atomicMaxF(float* addr, float val) {
    unsigned* ua = (unsigned*)addr;
    unsigned old = *ua;
    while (__uint_as_float(old) < val) {
        unsigned assumed = old;
        old = atomicCAS(ua, assumed, __float_as_uint(val));
        if (old == assumed) break;
    }
}

__device__ inline unsigned orderKey(float s) {
    unsigned b = __float_as_uint(s);
    return (b & 0x80000000u) ? ~b : (b | 0x80000000u);
}

// ballot-dedup LDS histogram insert: O(1) atomics per distinct bin per wave
__device__ inline void histAdd(int* sh, int bin, bool act, int nbits) {
    unsigned long long mm = __ballot(act);
    for (int b = 0; b < nbits; b++) {
        unsigned long long bal = __ballot(act && ((bin >> b) & 1));
        mm &= ((bin >> b) & 1) ? bal : ~bal;
    }
    if (act) {
        int lane = threadIdx.x & 63;
        int leader = __ffsll(mm) - 1;
        if (lane == leader) atomicAdd(&sh[bin], __popcll(mm));
    }
}

__device__ const float c_invk[10] = {
    1.0f/32000.0f, 1.0f/25600.0f, 1.0f/20480.0f, 1.0f/16384.0f, 1.0f/13108.0f,
    1.0f/10487.0f, 1.0f/8390.0f,  1.0f/6712.0f,  1.0f/5370.0f,  1.0f/4296.0f };

// selbuf slots: 0=bstar 1=rem 2=candcnt 3=thresh 4=cut 5=slotcnt

// ---------------------------------------------------------------- init (+ layer-0 degree count)
__global__ void k_init(const int* __restrict__ eidx, int* __restrict__ esrc,
                       int* __restrict__ edst, const float* __restrict__ poolp,
                       float* __restrict__ rbuf, float* __restrict__ pnorm,
                       int* __restrict__ ecnt, int* __restrict__ degA) {
    int b = blockIdx.x, t = threadIdx.x;
    if (b < 10) {
        rbuf[b*256 + t] = (t < 128) ? -3.402823e38f : 0.0f;
        __shared__ float red[256];
        float v = 0.0f;
        if (t < 128) { float pv = poolp[b*128 + t]; v = pv*pv; }
        red[t] = v; __syncthreads();
        for (int s = 128; s > 0; s >>= 1) { if (t < s) red[t] += red[t+s]; __syncthreads(); }
        if (t == 0) pnorm[b] = sqrtf(red[0]);
    }
    if (b == 10 && t < 16) ecnt[t] = (t == 0) ? NEDGE : 0;
    int e = b*256 + t;
    if (e < NEDGE) {
        int d = eidx[NEDGE + e];
        esrc[e] = eidx[e]; edst[e] = d;
        atomicAdd(&degA[d], 1);
    }
}

// ---------------------------------------------------------------- fused single-pass scan (decoupled lookback)
// also zeroes ghist + selbuf counters for the layer
__global__ void k_scan(const int* __restrict__ deg,
                       int* __restrict__ offs, int* __restrict__ cursor,
                       float* __restrict__ dinv,
                       int* __restrict__ ghist, int* __restrict__ selbuf,
                       int* __restrict__ lbsum, int* __restrict__ lbflag,
                       int n, int chunk, int epoch) {
    int b = blockIdx.x, t = threadIdx.x, lane = t & 63, wid = t >> 6;
    __shared__ int red[256];
    __shared__ int s_excl;
    __shared__ int wsum[4];
    __shared__ int s_carry;
    if (b == 0) {
        for (int jj = t; jj < 2048; jj += 256) ghist[jj] = 0;
        if (t == 0) { selbuf[2] = 0; selbuf[5] = 0; }
    }
    int start = b*chunk, end = min(start + chunk, n);
    // local sum
    int s = 0;
    for (int i = start + t; i < end; i += 256) s += deg[i];
    red[t] = s; __syncthreads();
    for (int st = 128; st > 0; st >>= 1) { if (t < st) red[t] += red[t+st]; __syncthreads(); }
    if (t == 0) {
        int total = red[0];
        int e1 = epoch*4 + 1, e2 = epoch*4 + 2;
        __hip_atomic_store(&lbsum[b*2], total, __ATOMIC_RELAXED, __HIP_MEMORY_SCOPE_AGENT);
        __hip_atomic_store(&lbflag[b], e1, __ATOMIC_RELEASE, __HIP_MEMORY_SCOPE_AGENT);
        int excl = 0;
        for (int p = b - 1; p >= 0; ) {
            int f;
            do { f = __hip_atomic_load(&lbflag[p], __ATOMIC_ACQUIRE, __HIP_MEMORY_SCOPE_AGENT); }
            while (f != e1 && f != e2);
            if (f == e2) { excl += __hip_atomic_load(&lbsum[p*2+1], __ATOMIC_RELAXED, __HIP_MEMORY_SCOPE_AGENT); break; }
            excl += __hip_atomic_load(&lbsum[p*2], __ATOMIC_RELAXED, __HIP_MEMORY_SCOPE_AGENT);
            p--;
        }
        __hip_atomic_store(&lbsum[b*2+1], excl + total, __ATOMIC_RELAXED, __HIP_MEMORY_SCOPE_AGENT);
        __hip_atomic_store(&lbflag[b], e2, __ATOMIC_RELEASE, __HIP_MEMORY_SCOPE_AGENT);
        s_excl = excl;
    }
    __syncthreads();
    if (t == 0) s_carry = s_excl;
    __syncthreads();
    // chunk-local scan
    for (int base = start; base < end; base += 256) {
        int i = base + t;
        int d = (i < end) ? deg[i] : 0;
        int incl = d;
        for (int off = 1; off < 64; off <<= 1) {
            int o = __shfl_up(incl, off);
            if (lane >= off) incl += o;
        }
        if (lane == 63) wsum[wid] = incl;
        __syncthreads();
        if (t == 0) { int c = s_carry; for (int w = 0; w < 4; w++) { int tmp = wsum[w]; wsum[w] = c; c += tmp; } s_carry = c; }
        __syncthreads();
        int p = wsum[wid] + incl - d;
        if (i < end) {
            offs[i] = p; cursor[i] = p;
            dinv[i] = (d > 0) ? 1.0f/sqrtf((float)d) : 0.0f;
        }
        __syncthreads();
    }
}

// ---------------------------------------------------------------- fused CSR fill + GEMM (K-tiled LDS W/V)
__global__ __launch_bounds__(128) void k_fillgemm(const int* __restrict__ esrc, const int* __restrict__ edst,
        int* __restrict__ cursor, int* __restrict__ csr, const int* __restrict__ ecnt,
        const float* __restrict__ h, const float* __restrict__ W, const float* __restrict__ V,
        const float* __restrict__ bias, float* __restrict__ HW, float* __restrict__ AGG, int n) {
    int b = blockIdx.x, t = threadIdx.x;
    if (b < FB) {
        int ec = *ecnt;
        for (int e = b*128 + t; e < ec; e += FB*128) {
            int pos = atomicAdd(&cursor[edst[e]], 1);
            csr[pos] = esrc[e];
        }
        return;
    }
    __shared__ __align__(16) float ht[128*36];     // h^T tile [k][r], stride 36
    __shared__ __align__(16) float wt[KT*128];
    __shared__ __align__(16) float vt[KT*128];
    int v0 = (b - FB) * GRB;
    for (int it = 0; it < GRB; it++)
        ht[t*36 + it] = h[(size_t)(v0 + it)*128 + t];
    float accW[GRB], accV[GRB];
    #pragma unroll
    for (int r = 0; r < GRB; r++) { accW[r] = 0.0f; accV[r] = 0.0f; }
    for (int k0 = 0; k0 < 128; k0 += KT) {
        __syncthreads();                           // ht ready / previous tile consumed
        const float4* Wp = (const float4*)(W + k0*128);
        const float4* Vp = (const float4*)(V + k0*128);
        float4* w4 = (float4*)wt;
        float4* v4 = (float4*)vt;
        #pragma unroll
        for (int q = 0; q < 4; q++) { w4[q*128 + t] = Wp[q*128 + t]; v4[q*128 + t] = Vp[q*128 + t]; }
        __syncthreads();
        for (int kk = 0; kk < KT; kk++) {
            float mw = wt[kk*128 + t];
            float mv = vt[kk*128 + t];
            const float* hp = &ht[(k0 + kk)*36];
            #pragma unroll
            for (int r4 = 0; r4 < GRB; r4 += 4) {
                float4 hq = *(const float4*)(hp + r4);
                accW[r4+0] += hq.x*mw;  accV[r4+0] += hq.x*mv;
                accW[r4+1] += hq.y*mw;  accV[r4+1] += hq.y*mv;
                accW[r4+2] += hq.z*mw;  accV[r4+2] += hq.z*mv;
                accW[r4+3] += hq.w*mw;  accV[r4+3] += hq.w*mv;
            }
        }
    }
    float bb = bias[t];
    for (int r = 0; r < GRB; r++) {
        int v = v0 + r;
        if (v >= n) break;
        HW[v*128 + t]  = accW[r];
        AGG[v*128 + t] = accV[r] + bb;
    }
}

// ---------------------------------------------------------------- layer-0 fused node update
__global__ __launch_bounds__(128) void k_gather0(
    const float* __restrict__ x, const float* __restrict__ W1, const float* __restrict__ V1,
    const float* __restrict__ convb,
    const float* __restrict__ bng, const float* __restrict__ bnb,
    const float* __restrict__ bnm, const float* __restrict__ bnv,
    const float* __restrict__ poolp, const float* __restrict__ pnorm,
    const float* __restrict__ prelua,
    const int* __restrict__ offs, const int* __restrict__ deg, const float* __restrict__ dinv,
    const int* __restrict__ csr,
    float* __restrict__ AGG, float* __restrict__ score, unsigned* __restrict__ keys) {
    int v = blockIdx.x, j = threadIdx.x;
    __shared__ float red[128];
    int off = offs[v], dg = deg[v];
    float accs = 0.0f;
    for (int c = j; c < dg; c += 128) { int s = csr[off + c]; accs += x[s]*dinv[s]; }
    red[j] = accs; __syncthreads();
    for (int st = 64; st > 0; st >>= 1) { if (j < st) red[j] += red[j+st]; __syncthreads(); }
    float aggs = red[0] * dinv[v];
    __syncthreads();
    float h2 = aggs*W1[j] + x[v]*V1[j] + convb[j];
    h2 = fmaxf(h2, 0.0f);
    float scale = bng[j] / sqrtf(bnv[j] + 1e-5f);
    h2 = (h2 - bnm[j])*scale + bnb[j];
    float a = prelua[0];
    h2 = (h2 > 0.0f) ? h2 : a*h2;
    AGG[v*128 + j] = h2;
    red[j] = h2 * poolp[j]; __syncthreads();
    for (int st = 64; st > 0; st >>= 1) { if (j < st) red[j] += red[j+st]; __syncthreads(); }
    if (j == 0) {
        float sc = tanhf(red[0] / pnorm[0]);
        score[v] = sc;
        keys[v]  = orderKey(sc);
    }
}

// ---------------------------------------------------------------- generic fused gather + update + score
__global__ __launch_bounds__(128) void k_gather(
    const float* __restrict__ HW, float* __restrict__ AGG,
    const int* __restrict__ offs, const int* __restrict__ deg, const float* __restrict__ dinv,
    const int* __restrict__ csr,
    const float* __restrict__ bng, const float* __restrict__ bnb,
    const float* __restrict__ bnm, const float* __restrict__ bnv,
    const float* __restrict__ poolp, const float* __restrict__ pnorm,
    const float* __restrict__ prelua,
    float* __restrict__ score, unsigned* __restrict__ keys, int layer) {
    int v = blockIdx.x, j = threadIdx.x;
    __shared__ int   s_src[128];
    __shared__ float s_dv[128];
    __shared__ float red[128];
    int off = offs[v], dg = deg[v];
    float acc = 0.0f;
    for (int base = 0; base < dg; base += 128) {
        int cnt = min(128, dg - base);
        if (j < cnt) { int s = csr[off + base + j]; s_src[j] = s; s_dv[j] = dinv[s]; }
        __syncthreads();
        for (int c = 0; c < cnt; c++) acc += HW[s_src[c]*128 + j] * s_dv[c];
        __syncthreads();
    }
    int gj = layer*128 + j;
    float h2 = AGG[v*128 + j] + acc*dinv[v];
    h2 = fmaxf(h2, 0.0f);
    float scale = bng[gj] / sqrtf(bnv[gj] + 1e-5f);
    h2 = (h2 - bnm[gj])*scale + bnb[gj];
    float a = prelua[0];
    h2 = (h2 > 0.0f) ? h2 : a*h2;
    AGG[v*128 + j] = h2;
    red[j] = h2 * poolp[gj]; __syncthreads();
    for (int st = 64; st > 0; st >>= 1) { if (j < st) red[j] += red[j+st]; __syncthreads(); }
    if (j == 0) {
        float sc = tanhf(red[0] / pnorm[layer]);
        score[v] = sc;
        keys[v]  = orderKey(sc);
    }
}

// ---------------------------------------------------------------- key histogram (ballot-dedup, degeneracy-safe)
__global__ void k_hist(const unsigned* __restrict__ keys, int* __restrict__ ghist, int n) {
    __shared__ int lh[2048];
    int t = threadIdx.x;
    for (int jj = t; jj < 2048; jj += 256) lh[jj] = 0;
    __syncthreads();
    int nR = (n + 255) & ~255;
    for (int i = blockIdx.x*256 + t; i < nR; i += gridDim.x*256) {
        bool act = (i < n);
        int bin = act ? (int)(keys[i] >> 21) : 0;
        histAdd(lh, bin, act, 11);
    }
    __syncthreads();
    for (int jj = t; jj < 2048; jj += 256) { int c = lh[jj]; if (c) atomicAdd(&ghist[jj], c); }
}

// ---------------------------------------------------------------- top-k stage 1: bin select + candidate collect (+degN zero)
__global__ __launch_bounds__(1024) void k_collect(const unsigned* __restrict__ keys,
                                                  const int* __restrict__ ghist,
                                                  int* __restrict__ selbuf,
                                                  unsigned* __restrict__ ckey, int* __restrict__ cidx,
                                                  int* __restrict__ degN, int n, int kk) {
    __shared__ int sh[2048];
    __shared__ int s_bstar, s_base, s_cur;
    __shared__ int red[1024];
    int t = threadIdx.x, lane = t & 63;
    for (int i = blockIdx.x*1024 + t; i < NMAX; i += gridDim.x*1024) degN[i] = 0;
    sh[t] = ghist[t]; sh[t+1024] = ghist[t+1024];
    __syncthreads();
    for (int off = 1; off < 2048; off <<= 1) {
        int v0 = sh[t]      + ((t+off < 2048)      ? sh[t+off]      : 0);
        int v1 = sh[t+1024] + ((t+1024+off < 2048) ? sh[t+1024+off] : 0);
        __syncthreads();
        sh[t] = v0; sh[t+1024] = v1;
        __syncthreads();
    }
    for (int d = t; d < 2048; d += 1024) {
        int S = sh[d], Sn = (d == 2047) ? 0 : sh[d+1];
        if (S >= kk && Sn < kk) {
            s_bstar = d;
            if (blockIdx.x == 0) { selbuf[0] = d; selbuf[1] = kk - Sn; }
        }
    }
    __syncthreads();
    int bstar = s_bstar;
    int cnt = 0;
    for (int i = blockIdx.x*1024 + t; i < n; i += gridDim.x*1024)
        cnt += ((int)(keys[i] >> 21) == bstar);
    red[t] = cnt; __syncthreads();
    for (int st = 512; st > 0; st >>= 1) { if (t < st) red[t] += red[t+st]; __syncthreads(); }
    if (t == 0) { s_base = atomicAdd(&selbuf[2], red[0]); s_cur = 0; }
    __syncthreads();
    for (int base = blockIdx.x*1024; base < n; base += gridDim.x*1024) {
        int i = base + t;
        bool keep = false; unsigned key = 0;
        if (i < n) { key = keys[i]; keep = ((int)(key >> 21) == bstar); }
        unsigned long long m = __ballot(keep);
        int wcnt = __popcll(m);
        int wbase = 0;
        if (lane == 0 && wcnt) wbase = atomicAdd(&s_cur, wcnt);
        wbase = __shfl(wbase, 0);
        if (keep) {
            int pos = s_base + wbase + __popcll(m & ((1ULL << lane) - 1));
            ckey[pos] = key; cidx[pos] = i;
        }
    }
}

// ---------------------------------------------------------------- top-k stage 2: O(m) refine
__global__ __launch_bounds__(1024) void k_refine2(const unsigned* __restrict__ ckey,
                                                  const int* __restrict__ cidx,
                                                  int* __restrict__ selbuf) {
    __shared__ int sh[2048];
    __shared__ int s_dA, s_remA, s_dB, s_ntk, s_bC, s_rem2, s_cut;
    int t = threadIdx.x;
    int m = selbuf[2], rem = selbuf[1];
    int mR = (m + 1023) & ~1023;

    sh[t] = 0; sh[t+1024] = 0;
    __syncthreads();
    for (int i = t; i < mR; i += 1024) {
        bool act = (i < m);
        int bin = act ? (int)((ckey[i] >> 10) & 2047) : 0;
        histAdd(sh, bin, act, 11);
    }
    __syncthreads();
    for (int off = 1; off < 2048; off <<= 1) {
        int v0 = sh[t]      + ((t+off < 2048)      ? sh[t+off]      : 0);
        int v1 = sh[t+1024] + ((t+1024+off < 2048) ? sh[t+1024+off] : 0);
        __syncthreads();
        sh[t] = v0; sh[t+1024] = v1;
        __syncthreads();
    }
    for (int d = t; d < 2048; d += 1024) {
        int S = sh[d], Sn = (d == 2047) ? 0 : sh[d+1];
        if (S >= rem && Sn < rem) { s_dA = d; s_remA = rem - Sn; }
    }
    __syncthreads();
    int dA = s_dA, remA = s_remA;

    sh[t] = 0;
    __syncthreads();
    for (int i = t; i < mR; i += 1024) {
        bool act = (i < m) && ((int)((ckey[i] >> 10) & 2047) == dA);
        int bin = act ? (int)(ckey[i] & 1023) : 0;
        histAdd(sh, bin, act, 10);
    }
    __syncthreads();
    for (int off = 1; off < 1024; off <<= 1) {
        int v0 = sh[t] + ((t+off < 1024) ? sh[t+off] : 0);
        __syncthreads();
        sh[t] = v0;
        __syncthreads();
    }
    {
        int S = sh[t], Sn = (t == 1023) ? 0 : sh[t+1];
        if (S >= remA && Sn < remA) { s_dB = t; s_ntk = remA - Sn; }
    }
    __syncthreads();
    unsigned thresh = ((unsigned)selbuf[0] << 21) | ((unsigned)dA << 10) | (unsigned)s_dB;
    int ntk = s_ntk;

    if (t < 256) sh[t] = 0;
    __syncthreads();
    for (int i = t; i < mR; i += 1024) {
        bool act = (i < m) && (ckey[i] == thresh);
        int bin = act ? (cidx[i] >> 8) : 0;
        histAdd(sh, bin, act, 8);
    }
    __syncthreads();
    for (int off = 1; off < 256; off <<= 1) {
        int v = 0;
        if (t < 256) v = sh[t] + ((t >= off) ? sh[t-off] : 0);
        __syncthreads();
        if (t < 256) sh[t] = v;
        __syncthreads();
    }
    if (t < 256) {
        int P = sh[t], Pp = (t == 0) ? 0 : sh[t-1];
        if (P >= ntk && Pp < ntk) { s_bC = t; s_rem2 = ntk - Pp; }
    }
    __syncthreads();
    int bC = s_bC, rem2 = s_rem2;

    if (t < 256) sh[t] = 0;
    __syncthreads();
    for (int i = t; i < mR; i += 1024) {
        bool act = (i < m) && (ckey[i] == thresh) && ((cidx[i] >> 8) == bC);
        int bin = act ? (cidx[i] & 255) : 0;
        histAdd(sh, bin, act, 8);
    }
    __syncthreads();
    for (int off = 1; off < 256; off <<= 1) {
        int v = 0;
        if (t < 256) v = sh[t] + ((t >= off) ? sh[t-off] : 0);
        __syncthreads();
        if (t < 256) sh[t] = v;
        __syncthreads();
    }
    if (t < 256) {
        int P = sh[t], Pp = (t == 0) ? 0 : sh[t-1];
        if (P >= rem2 && Pp < rem2) s_cut = (bC << 8) | t;
    }
    __syncthreads();
    if (t == 0) { selbuf[3] = (int)thresh; selbuf[4] = s_cut; selbuf[5] = 0; }
}

// ---------------------------------------------------------------- top-k stage 3: compaction
__global__ void k_compact(const unsigned* __restrict__ keys, int* __restrict__ selbuf,
                          int* __restrict__ remap, int* __restrict__ keep_ids, int n) {
    unsigned thresh = (unsigned)selbuf[3];
    int cut = selbuf[4];
    int t = threadIdx.x, lane = t & 63;
    __shared__ int s_base, s_cur;
    __shared__ int red[256];
    int cnt = 0;
    for (int base = blockIdx.x*256; base < n; base += gridDim.x*256) {
        int i = base + t;
        if (i < n) {
            unsigned key = keys[i];
            cnt += (key > thresh) || (key == thresh && i <= cut);
        }
    }
    red[t] = cnt; __syncthreads();
    for (int st = 128; st > 0; st >>= 1) { if (t < st) red[t] += red[t+st]; __syncthreads(); }
    if (t == 0) { s_base = atomicAdd(&selbuf[5], red[0]); s_cur = 0; }
    __syncthreads();
    for (int base = blockIdx.x*256; base < n; base += gridDim.x*256) {
        int i = base + t;
        bool keep = false;
        if (i < n) {
            unsigned key = keys[i];
            keep = (key > thresh) || (key == thresh && i <= cut);
        }
        unsigned long long m = __ballot(keep);
        int wcnt = __popcll(m);
        int wbase = 0;
        if (lane == 0 && wcnt) wbase = atomicAdd(&s_cur, wcnt);
        wbase = __shfl(wbase, 0);
        if (keep) {
            int slot = s_base + wbase + __popcll(m & ((1ULL << lane) - 1));
            remap[i] = slot; keep_ids[slot] = i;
        } else if (i < n) remap[i] = -1;
    }
}

// ---------------------------------------------------------------- pool + edge remap/compact (+next-layer degree)
__global__ void k_pool(const float* __restrict__ AGG, const float* __restrict__ score,
                       const int* __restrict__ keep_ids, const int* __restrict__ remap,
                       float* __restrict__ H, float* __restrict__ rbuf,
                       const int* __restrict__ esrcP, const int* __restrict__ edstP,
                       int* __restrict__ esrcN, int* __restrict__ edstN,
                       const int* __restrict__ ecntP, int* __restrict__ ecntN,
                       int* __restrict__ degN, int k, int layer) {
    int b = blockIdx.x, t = threadIdx.x;
    if (b < PBLK) {
        int sub = t >> 7, j = t & 127;
        float lmax = -3.402823e38f, lsum = 0.0f;
        int s = b*2 + sub;
        int v = (s < k) ? keep_ids[s] : 0;
        while (s < k) {
            float sc = score[v];
            float val = AGG[v*128 + j] * sc;
            int s2 = s + PBLK*2;
            int v2 = (s2 < k) ? keep_ids[s2] : 0;
            H[s*128 + j] = val;
            lmax = fmaxf(lmax, val); lsum += val;
            s = s2; v = v2;
        }
        __shared__ float shm[256], shs[256];
        shm[t] = lmax; shs[t] = lsum;
        __syncthreads();
        if (sub == 0) {
            lmax = fmaxf(shm[j], shm[j+128]);
            lsum = shs[j] + shs[j+128];
            atomicMaxF(&rbuf[layer*256 + j], lmax);
            atomicAdd(&rbuf[layer*256 + 128 + j], lsum);
        }
    } else {
        int eb = b - PBLK, lane = t & 63;
        int ec = *ecntP;
        __shared__ int s_base, s_cur;
        __shared__ int red[256];
        int cnt = 0;
        for (int base = eb*256; base < ec; base += EBLK*256) {
            int e = base + t;
            if (e < ec) {
                int ns = remap[esrcP[e]], nd = remap[edstP[e]];
                cnt += (ns >= 0 && nd >= 0);
            }
        }
        red[t] = cnt; __syncthreads();
        for (int st = 128; st > 0; st >>= 1) { if (t < st) red[t] += red[t+st]; __syncthreads(); }
        if (t == 0) { s_base = atomicAdd(ecntN, red[0]); s_cur = 0; }
        __syncthreads();
        for (int base = eb*256; base < ec; base += EBLK*256) {
            int e = base + t;
            bool keep = false; int ns = 0, nd = 0;
            if (e < ec) {
                ns = remap[esrcP[e]]; nd = remap[edstP[e]];
                keep = (ns >= 0 && nd >= 0);
            }
            unsigned long long m = __ballot(keep);
            int wcnt = __popcll(m);
            int wbase = 0;
            if (lane == 0 && wcnt) wbase = atomicAdd(&s_cur, wcnt);
            wbase = __shfl(wbase, 0);
            if (keep) {
                int pos = s_base + wbase + __popcll(m & ((1ULL << lane) - 1));
                esrcN[pos] = ns; edstN[pos] = nd;
                atomicAdd(&degN[nd], 1);
            }
        }
    }
}

// ---------------------------------------------------------------- MLP head
__global__ __launch_bounds__(320) void k_lin1(const float* __restrict__ rbuf,
                                              const float* __restrict__ w1,
                                              float* __restrict__ z1part) {
    int b = blockIdx.x, t = threadIdx.x;
    int j = t*4;
    float4 acc = make_float4(0.f, 0.f, 0.f, 0.f);
    int i0 = b*40;
    for (int r = 0; r < 40; r++) {
        int i = i0 + r;
        float rv = rbuf[i];
        if (i & 128) rv *= c_invk[i >> 8];
        float4 w = *(const float4*)(w1 + (size_t)i*1280 + j);
        acc.x += rv*w.x; acc.y += rv*w.y; acc.z += rv*w.z; acc.w += rv*w.w;
    }
    *(float4*)(z1part + b*1280 + j) = acc;
}

__global__ __launch_bounds__(320) void k_lin2(const float* __restrict__ z1part,
                                              const float* __restrict__ b1,
                                              const float* __restrict__ w2, const float* __restrict__ b2,
                                              const float* __restrict__ prelua, float* __restrict__ out) {
    int t = threadIdx.x, lane = t & 63, wid = t >> 6;
    float a = prelua[0];
    int j = t*4;
    float4 acc = make_float4(0.f, 0.f, 0.f, 0.f);
    for (int p = 0; p < LIN1B; p++) {
        float4 v = *(const float4*)(z1part + p*1280 + j);
        acc.x += v.x; acc.y += v.y; acc.z += v.z; acc.w += v.w;
    }
    float4 bb = *(const float4*)(b1 + j);
    float z0 = acc.x + bb.x; z0 = z0 > 0.f ? z0 : a*z0;
    float z1 = acc.y + bb.y; z1 = z1 > 0.f ? z1 : a*z1;
    float z2 = acc.z + bb.z; z2 = z2 > 0.f ? z2 : a*z2;
    float z3 = acc.w + bb.w; z3 = z3 > 0.f ? z3 : a*z3;
    float s[8];
    #pragma unroll
    for (int o = 0; o < 8; o++)
        s[o] = z0*w2[(j+0)*8+o] + z1*w2[(j+1)*8+o] + z2*w2[(j+2)*8+o] + z3*w2[(j+3)*8+o];
    #pragma unroll
    for (int off = 32; off > 0; off >>= 1)
        #pragma unroll
        for (int o = 0; o < 8; o++) s[o] += __shfl_down(s[o], off);
    __shared__ float sred[5][8];
    if (lane == 0)
        for (int o = 0; o < 8; o++) sred[wid][o] = s[o];
    __syncthreads();
    if (t == 0) {
        float zo[8];
        for (int o = 0; o < 8; o++) {
            float z = sred[0][o]+sred[1][o]+sred[2][o]+sred[3][o]+sred[4][o] + b2[o];
            zo[o] = z > 0.f ? z : a*z;
        }
        float mn = zo[0];
        for (int o = 1; o < 8; o++) mn = fminf(mn, zo[o]);
        float v[8], mx = -3.402823e38f;
        for (int o = 0; o < 8; o++) { v[o] = zo[o] - mn; mx = fmaxf(mx, v[o]); }
        float sm = 0.f;
        for (int o = 0; o < 8; o++) { v[o] = v[o] / mx; sm += v[o]; }
        for (int o = 0; o < 8; o++) out[o] = v[o] / sm;
    }
}

// ---------------------------------------------------------------- launch
extern "C" void kernel_launch(void* const* d_in, const int* in_sizes, int n_in,
                              void* d_out, int out_size, void* d_ws, size_t ws_size,
                              hipStream_t stream) {
    const float* x      = (const float*)d_in[0];
    const int*   eidx   = (const int*)  d_in[1];
    const float* W1     = (const float*)d_in[2];
    const float* V1     = (const float*)d_in[3];
    const float* Ws     = (const float*)d_in[4];
    const float* Vs     = (const float*)d_in[5];
    const float* convb  = (const float*)d_in[6];
    const float* bng    = (const float*)d_in[7];
    const float* bnb    = (const float*)d_in[8];
    const float* bnm    = (const float*)d_in[9];
    const float* bnv    = (const float*)d_in[10];
    const float* poolp  = (const float*)d_in[11];
    const float* prelua = (const float*)d_in[12];
    const float* w1     = (const float*)d_in[13];
    const float* b1     = (const float*)d_in[14];
    const float* w2     = (const float*)d_in[15];
    const float* b2     = (const float*)d_in[16];
    float* out = (float*)d_out;

    float* wsf  = (float*)d_ws;
    float* H      = wsf;
    float* HW     = H     + (size_t)NMAX*128;
    float* AGG    = HW    + (size_t)NMAX*128;
    float* dinv   = AGG   + (size_t)NMAX*128;
    float* score  = dinv  + NMAX;
    float* rbuf   = score + NMAX;
    float* pnorm  = rbuf  + 2560;
    float* z1part = pnorm + 16;                  // LIN1B*1280
    unsigned* keys = (unsigned*)(z1part + LIN1B*1280);
    int* esrcA  = (int*)(keys + NMAX);
    int* edstA  = esrcA + NEDGE;
    int* esrcB  = edstA + NEDGE;
    int* edstB  = esrcB + NEDGE;
    int* csr    = edstB + NEDGE;
    int* degA   = csr   + NEDGE;
    int* degB   = degA  + NMAX;
    int* ghist  = degB  + NMAX;                  // 2048
    int* offs   = ghist + 2048;
    int* cursor = offs  + NMAX;
    int* remap  = cursor + NMAX;
    int* keep_ids = remap + NMAX;
    unsigned* ckey = (unsigned*)(keep_ids + NMAX);
    int* cidx   = (int*)(ckey + NMAX);
    int* lbsum  = cidx  + NMAX;                  // SB*2
    int* lbflag = lbsum + SB*2;                  // SB
    int* ecnt   = lbflag + SB;                   // 16
    int* selbuf = ecnt  + 16;                    // 16

    static const int NS[10] = {40000,32000,25600,20480,16384,13108,10487,8390,6712,5370};
    static const int KS[10] = {32000,25600,20480,16384,13108,10487,8390,6712,5370,4296};

    hipMemsetAsync(degA, 0, (size_t)NMAX*sizeof(int), stream);
    k_init<<<2500, 256, 0, stream>>>(eidx, esrcA, edstA, poolp, rbuf, pnorm, ecnt, degA);

    for (int i = 0; i < 10; i++) {
        int n = NS[i], k = KS[i];
        int chunk = (n + SB - 1) / SB;
        int* esrcP = (i & 1) ? esrcB : esrcA;
        int* edstP = (i & 1) ? edstB : edstA;
        int* esrcN = (i & 1) ? esrcA : esrcB;
        int* edstN = (i & 1) ? edstA : edstB;
        int* degP  = (i & 1) ? degB : degA;
        int* degN  = (i & 1) ? degA : degB;

        k_scan<<<SB, 256, 0, stream>>>(degP, offs, cursor, dinv, ghist, selbuf,
                                       lbsum, lbflag, n, chunk, i + 1);

        int gb = (i == 0) ? 0 : (n + GRB - 1) / GRB;
        k_fillgemm<<<FB + gb, 128, 0, stream>>>(esrcP, edstP, cursor, csr, &ecnt[i],
                                                H, (i == 0) ? W1 : Ws + (size_t)(i-1)*16384,
                                                (i == 0) ? V1 : Vs + (size_t)(i-1)*16384,
                                                convb + i*128, HW, AGG, n);

        if (i == 0) {
            k_gather0<<<n, 128, 0, stream>>>(x, W1, V1, convb,
                                             bng, bnb, bnm, bnv, poolp, pnorm, prelua,
                                             offs, degP, dinv, csr, AGG, score, keys);
        } else {
            k_gather<<<n, 128, 0, stream>>>(HW, AGG, offs, degP, dinv, csr,
                                            bng, bnb, bnm, bnv, poolp, pnorm, prelua,
                                            score, keys, i);
        }

        k_hist   <<<32, 256, 0, stream>>>(keys, ghist, n);
        k_collect<<<32, 1024, 0, stream>>>(keys, ghist, selbuf, ckey, cidx, degN, n, k);
        k_refine2<<<1, 1024, 0, stream>>>(ckey, cidx, selbuf);
        k_compact<<<64, 256, 0, stream>>>(keys, selbuf, remap, keep_ids, n);

        k_pool<<<PBLK + EBLK, 256, 0, stream>>>(AGG, score, keep_ids, remap, H, rbuf,
                                                esrcP, edstP, esrcN, edstN,
                                                &ecnt[i], &ecnt[i+1], degN, k, i);
    }

    k_lin1<<<LIN1B, 320, 0, stream>>>(rbuf, w1, z1part);
    k_lin2<<<1, 320, 0, stream>>>(z1part, b1, w2, b2, prelua, out);
}